// Round 6
// baseline (879.502 us; speedup 1.0000x reference)
//
#include <hip/hip_runtime.h>
#include <hip/hip_bf16.h>
#include <cstdint>
#include <cstddef>

#define NN 16000
#define EE 256000
#define ETOT (EE + NN)
#define RREL 8
#define NHEAD 8
#define DOUT 64
#define HD 512
#define NEG 0.2f

typedef unsigned int u32;
typedef short bf16x8 __attribute__((ext_vector_type(8)));
typedef float f32x4 __attribute__((ext_vector_type(4)));

// ---------- helpers ----------
__device__ inline unsigned short f2bf(float f) {
  u32 i = __float_as_uint(f);
  u32 r = (i + 0x7fff + ((i >> 16) & 1)) >> 16;  // RNE, finite values
  return (unsigned short)r;
}
__device__ inline float bf2f(unsigned short h) {
  return __uint_as_float((u32)h << 16);
}
__device__ inline float2 load2(const float* p) { return *(const float2*)p; }
__device__ inline float2 load2(const unsigned short* p) {
  u32 v = *(const u32*)p;
  float lo = __uint_as_float((v & 0xffffu) << 16);
  float hi = __uint_as_float(v & 0xffff0000u);
  return make_float2(lo, hi);
}
__device__ inline void g2lds16(const void* g, void* lds) {
  __builtin_amdgcn_global_load_lds(
      (const __attribute__((address_space(1))) unsigned int*)g,
      (__attribute__((address_space(3))) unsigned int*)lds, 16, 0, 0);
}
// wide row store: 32 values from vals[] -> global, bf16 or f32
__device__ inline void storeRow(unsigned short* p, const float* v) {
#pragma unroll
  for (int g = 0; g < 4; ++g) {
    uint4 w;
    w.x = (u32)f2bf(v[g * 8 + 0]) | ((u32)f2bf(v[g * 8 + 1]) << 16);
    w.y = (u32)f2bf(v[g * 8 + 2]) | ((u32)f2bf(v[g * 8 + 3]) << 16);
    w.z = (u32)f2bf(v[g * 8 + 4]) | ((u32)f2bf(v[g * 8 + 5]) << 16);
    w.w = (u32)f2bf(v[g * 8 + 6]) | ((u32)f2bf(v[g * 8 + 7]) << 16);
    *(uint4*)(p + g * 8) = w;
  }
}
__device__ inline void storeRow(float* p, const float* v) {
#pragma unroll
  for (int g = 0; g < 8; ++g)
    *(float4*)(p + g * 4) = make_float4(v[g * 4], v[g * 4 + 1], v[g * 4 + 2], v[g * 4 + 3]);
}

// ---------- preprocessing ----------
__global__ void k_max_et(const int* __restrict__ et, int* meta) {
  int e = blockIdx.x * 256 + threadIdx.x;
  if (e < EE) atomicMax(&meta[0], et[e]);
}

__global__ void k_hist(const int* __restrict__ ei, int* __restrict__ deg) {
  int e = blockIdx.x * 256 + threadIdx.x;
  if (e >= ETOT) return;
  int dst = (e < EE) ? ei[EE + e] : (e - EE);
  atomicAdd(&deg[dst], 1);
}

__global__ __launch_bounds__(1024) void k_scan(const int* __restrict__ deg,
                                               int* __restrict__ rowptr,
                                               int* __restrict__ fill) {
  __shared__ int sm[1024];
  __shared__ int carry;
  if (threadIdx.x == 0) carry = 0;
  __syncthreads();
  for (int base = 0; base < NN; base += 1024) {
    int i = base + threadIdx.x;
    int v = (i < NN) ? deg[i] : 0;
    sm[threadIdx.x] = v;
    __syncthreads();
    for (int off = 1; off < 1024; off <<= 1) {
      int t = (threadIdx.x >= off) ? sm[threadIdx.x - off] : 0;
      __syncthreads();
      sm[threadIdx.x] += t;
      __syncthreads();
    }
    int incl = sm[threadIdx.x] + carry;
    if (i < NN) { rowptr[i] = incl - v; fill[i] = incl - v; }
    __syncthreads();
    if (threadIdx.x == 1023) carry = incl;
    __syncthreads();
  }
  if (threadIdx.x == 0) rowptr[NN] = carry;
}

__global__ void k_scatter(const int* __restrict__ ei, const int* __restrict__ et,
                          const float* __restrict__ ea, const int* __restrict__ meta,
                          int* __restrict__ fill, int* __restrict__ csr_src,
                          int* __restrict__ csr_et, float* __restrict__ csr_ea) {
  int e = blockIdx.x * 256 + threadIdx.x;
  if (e >= ETOT) return;
  int src, dst, r; float a;
  if (e < EE) { src = ei[e]; dst = ei[EE + e]; r = et[e]; a = ea[e]; }
  else { src = dst = e - EE; r = (meta[0] + 1) & (RREL - 1); a = 0.5f; }
  int pos = atomicAdd(&fill[dst], 1);
  csr_src[pos] = src; csr_et[pos] = r; csr_ea[pos] = a;
}

// ---------- per-layer small precomputes ----------
__global__ void k_cvec(const float* __restrict__ We, const float* __restrict__ e,
                       float* __restrict__ cvec) {
  int j = threadIdx.x;
  if (j >= NHEAD) return;
  float acc = 0.f;
  for (int h = 0; h < HD; ++h) acc += We[h] * e[h * NHEAD + j];
  cvec[j] = acc;
}

// WQK[f, r*16 + j] : j<8 -> W[r,f,:]@q[:,j] ; j>=8 -> W[r,f,:]@k[:,j-8]
__global__ void k_wqk(const float* __restrict__ W, const float* __restrict__ q,
                      const float* __restrict__ k, float* __restrict__ WQK, int F) {
  int g = blockIdx.x * 256 + threadIdx.x;
  int j = g & 15;
  int rf = g >> 4;  // r*F + f
  int r = rf / F, f = rf % F;
  const float* wrow = W + (size_t)rf * HD;
  const float* qk = ((j < 8) ? q : k) + (j & 7);
  float acc = 0.f;
  for (int h = 0; h < HD; ++h) acc += wrow[h] * qk[(size_t)h * NHEAD];
  WQK[(size_t)f * 128 + r * 16 + j] = acc;
}

// ---------- split-bf16 operand builders (2-term: A=[hi|lo], B=[hi;hi]) ----
__global__ void k_asplit(const float* __restrict__ in, unsigned short* __restrict__ A2,
                         int F) {
  long idx = (long)blockIdx.x * 256 + threadIdx.x;  // over NN * F/4
  long total = (long)NN * (F >> 2);
  if (idx >= total) return;
  int row = (int)(idx / (F >> 2));
  int c4 = (int)(idx % (F >> 2)) << 2;
  float4 v = *(const float4*)&in[(size_t)row * F + c4];
  ushort4 hi, lo;
  hi.x = f2bf(v.x); hi.y = f2bf(v.y); hi.z = f2bf(v.z); hi.w = f2bf(v.w);
  lo.x = f2bf(v.x - bf2f(hi.x)); lo.y = f2bf(v.y - bf2f(hi.y));
  lo.z = f2bf(v.z - bf2f(hi.z)); lo.w = f2bf(v.w - bf2f(hi.w));
  unsigned short* base = A2 + (size_t)row * 2 * F;
  *(ushort4*)&base[c4] = hi;
  *(ushort4*)&base[F + c4] = lo;
}

// W: [R][F][512] f32 -> BT: [R][512][2F] bf16, BT[r][c][k'] = hi of W[r][k'%F][c]
__global__ __launch_bounds__(256) void k_bsplit(const float* __restrict__ W,
                                                unsigned short* __restrict__ BT, int F) {
  int f0 = blockIdx.x * 64, c0 = blockIdx.y * 64, r = blockIdx.z;
  __shared__ float tile[64][65];
  int tid = threadIdx.x;
  int i0 = tid >> 6;   // 0..3
  int j = tid & 63;
  const float* Wr = W + (size_t)r * F * 512;
  for (int i = i0; i < 64; i += 4)
    tile[i][j] = Wr[(size_t)(f0 + i) * 512 + c0 + j];
  __syncthreads();
  unsigned short* Br = BT + (size_t)r * 512 * 2 * F;
  for (int c = i0; c < 64; c += 4) {
    float v = tile[j][c];  // W[r][f0+j][c0+c]
    unsigned short hi = f2bf(v);
    unsigned short* dst = Br + (size_t)(c0 + c) * 2 * F + f0 + j;
    dst[0] = hi; dst[F] = hi;
  }
}

// ---------- MFMA GEMM: C[r] = A2 @ B_cat[r]  (bf16 in, f32 acc) ----------
// 128x128 tile, BK=32, 4 waves of 64x64, fragment-ordered LDS (conflict-free).
// Depth-2 prefetch: 3 LDS buffers, counted vmcnt + raw s_barrier.
// XCD decode: m fastest -> B panel (<=1MB/relation) L2-resident per XCD;
// A2 streamed in lockstep by all XCDs through L3 (one HBM fetch per line).
// Epilogue: acc -> LDS (ds_write_b128, [col][row] pad 68) -> coalesced
// dwordx4 stores (8x fewer store instructions than per-element).
template <typename TC>
__global__ __launch_bounds__(256) void k_mgemm(const unsigned short* __restrict__ A2,
                                               const unsigned short* __restrict__ BT,
                                               TC* __restrict__ C, int Kp,
                                               long cstride) {
  const int bid = blockIdx.x;
  const int xcd = bid & 7;
  const int v = xcd * 500 + (bid >> 3);   // 4000 = 8 * 500, bijective
  const int nr = v / 125;                 // (n0, r), slow: 4 per XCD
  const int mb = v - nr * 125;            // m-panel, fastest
  const int n0 = (nr & 3) << 7;
  const int r = nr >> 2;

  const unsigned short* Br = BT + (size_t)r * 512 * Kp;
  TC* Cr = C + (size_t)r * cstride;
  const int m0 = mb * 128;

  __shared__ __align__(16) unsigned char smem[49152];
  unsigned short* Asm = (unsigned short*)smem;             // [3][4096]
  unsigned short* Bsm = (unsigned short*)(smem + 24576);   // [3][4096]

  const int tid = threadIdx.x;
  const int wid = tid >> 6;
  const int lane = tid & 63;
  const int wr = wid >> 1, wc = wid & 1;
  const int rlow = lane & 15;
  const int kch = lane >> 4;  // k-chunk 0..3

  const unsigned short* gA0 = A2 + (size_t)(m0 + wid * 16 + rlow) * Kp + kch * 8;
  const unsigned short* gA1 = A2 + (size_t)(m0 + (wid + 4) * 16 + rlow) * Kp + kch * 8;
  const unsigned short* gB0 = Br + (size_t)(n0 + wid * 16 + rlow) * Kp + kch * 8;
  const unsigned short* gB1 = Br + (size_t)(n0 + (wid + 4) * 16 + rlow) * Kp + kch * 8;

  f32x4 acc[4][4] = {};
  const int nt = Kp >> 5;

  // prologue: stage buffers 0 and 1 (8 vm-ops per wave)
#pragma unroll
  for (int p = 0; p < 2; ++p) {
    const int k0 = p << 5;
    g2lds16(gA0 + k0, &Asm[p * 4096 + wid * 512]);
    g2lds16(gA1 + k0, &Asm[p * 4096 + (wid + 4) * 512]);
    g2lds16(gB0 + k0, &Bsm[p * 4096 + wid * 512]);
    g2lds16(gB1 + k0, &Bsm[p * 4096 + (wid + 4) * 512]);
  }

  int buf = 0;
  for (int t = 0; t < nt; ++t) {
    if (t + 1 < nt) {
      asm volatile("s_waitcnt vmcnt(4) lgkmcnt(0)" ::: "memory");
    } else {
      asm volatile("s_waitcnt vmcnt(0) lgkmcnt(0)" ::: "memory");
    }
    __builtin_amdgcn_s_barrier();
    asm volatile("" ::: "memory");
    if (t + 2 < nt) {
      const int k0 = (t + 2) << 5;
      int nb = buf + 2; if (nb >= 3) nb -= 3;
      g2lds16(gA0 + k0, &Asm[nb * 4096 + wid * 512]);
      g2lds16(gA1 + k0, &Asm[nb * 4096 + (wid + 4) * 512]);
      g2lds16(gB0 + k0, &Bsm[nb * 4096 + wid * 512]);
      g2lds16(gB1 + k0, &Bsm[nb * 4096 + (wid + 4) * 512]);
    }
    bf16x8 af[4], bfr[4];
#pragma unroll
    for (int i = 0; i < 4; ++i)
      af[i] = *(const bf16x8*)&Asm[buf * 4096 + (wr * 4 + i) * 512 + lane * 8];
#pragma unroll
    for (int j = 0; j < 4; ++j)
      bfr[j] = *(const bf16x8*)&Bsm[buf * 4096 + (wc * 4 + j) * 512 + lane * 8];
#pragma unroll
    for (int i = 0; i < 4; ++i)
#pragma unroll
      for (int j = 0; j < 4; ++j)
        acc[i][j] = __builtin_amdgcn_mfma_f32_16x16x32_bf16(af[i], bfr[j], acc[i][j],
                                                            0, 0, 0);
    buf = (buf == 2) ? 0 : buf + 1;
  }

  // ---- epilogue via LDS transpose, two 64-row passes ----
  __syncthreads();
  float* eps_f = (float*)smem;  // [128 cols][68 pad] f32 = 34.8 KB
#pragma unroll
  for (int p = 0; p < 2; ++p) {
    if (p) __syncthreads();
    if (wr == p) {
#pragma unroll
      for (int i = 0; i < 4; ++i)
#pragma unroll
        for (int j = 0; j < 4; ++j) {
          int col = wc * 64 + j * 16 + rlow;
          int row = i * 16 + kch * 4;
          *(f32x4*)&eps_f[col * 68 + row] = acc[i][j];
        }
    }
    __syncthreads();
    int row = tid >> 2;            // 0..63
    int cg = (tid & 3) * 32;       // col group base
    float vals[32];
#pragma unroll
    for (int c = 0; c < 32; ++c) vals[c] = eps_f[(cg + c) * 68 + row];
    storeRow(&Cr[(size_t)(m0 + p * 64 + row) * HD + n0 + cg], vals);
  }
}

// ---------- small fp32 GEMM (for qkbuf): C = A @ B, B:[F][128] ----------
__global__ __launch_bounds__(256) void k_gemm(const float* __restrict__ A,
                                              const float* __restrict__ B,
                                              float* __restrict__ C, int F) {
  const int m0 = blockIdx.x * 128;
  __shared__ float As[16][132];
  __shared__ float Bs[16][132];
  const int tid = threadIdx.x;
  const int arow = tid >> 2;
  const int acol = (tid & 3) << 2;
  const int brow = tid >> 5;
  const int bcol = (tid & 31) << 2;
  const int tr = ((tid >> 4) & 15) << 2;
  const int tc = (tid & 15) << 2;
  float acc[8][8] = {};
  for (int k0 = 0; k0 < F; k0 += 16) {
    float4 a0 = *(const float4*)&A[(size_t)(m0 + arow) * F + k0 + acol];
    float4 a1 = *(const float4*)&A[(size_t)(m0 + arow + 64) * F + k0 + acol];
    float4 b0 = *(const float4*)&B[(size_t)(k0 + brow) * 128 + bcol];
    float4 b1 = *(const float4*)&B[(size_t)(k0 + brow + 8) * 128 + bcol];
    As[acol + 0][arow] = a0.x; As[acol + 1][arow] = a0.y;
    As[acol + 2][arow] = a0.z; As[acol + 3][arow] = a0.w;
    As[acol + 0][arow + 64] = a1.x; As[acol + 1][arow + 64] = a1.y;
    As[acol + 2][arow + 64] = a1.z; As[acol + 3][arow + 64] = a1.w;
    *(float4*)&Bs[brow][bcol] = b0;
    *(float4*)&Bs[brow + 8][bcol] = b1;
    __syncthreads();
#pragma unroll
    for (int k = 0; k < 16; ++k) {
      float a[8], b[8];
      *(float4*)(a) = *(const float4*)&As[k][tr];
      *(float4*)(a + 4) = *(const float4*)&As[k][tr + 64];
      *(float4*)(b) = *(const float4*)&Bs[k][tc];
      *(float4*)(b + 4) = *(const float4*)&Bs[k][tc + 64];
#pragma unroll
      for (int i = 0; i < 8; ++i)
#pragma unroll
        for (int j = 0; j < 8; ++j)
          acc[i][j] = fmaf(a[i], b[j], acc[i][j]);
    }
    __syncthreads();
  }
#pragma unroll
  for (int i = 0; i < 8; ++i) {
    int row = m0 + tr + ((i < 4) ? i : (60 + i));
    *(float4*)&C[(size_t)row * 128 + tc] = make_float4(acc[i][0], acc[i][1], acc[i][2], acc[i][3]);
    *(float4*)&C[(size_t)row * 128 + tc + 64] = make_float4(acc[i][4], acc[i][5], acc[i][6], acc[i][7]);
  }
}

// ---------- fused attention + aggregation, one block per dst node ----------
template <typename T, int CONCAT>
__global__ __launch_bounds__(256) void k_attn(const T* __restrict__ t,
    const float* __restrict__ qkbuf, const float* __restrict__ cvec,
    const int* __restrict__ rowptr, const int* __restrict__ csr_src,
    const int* __restrict__ csr_et, const float* __restrict__ csr_ea,
    const float* __restrict__ bias, float* __restrict__ out) {
  const int n = blockIdx.x;
  const int tid = threadIdx.x;
  const int h = tid >> 5;  // head of elements 2*tid, 2*tid+1
  const int e0 = rowptr[n], e1 = rowptr[n + 1];
  const float ch = cvec[h];
  const float* qrow = qkbuf + (size_t)n * 128;
  float m = -1e30f, l = 0.f, acc0 = 0.f, acc1 = 0.f;
  for (int e = e0; e < e1; ++e) {
    int s = csr_src[e];
    int r = csr_et[e];
    float a = csr_ea[e];
    float logit = qrow[r * 16 + h]
                + qkbuf[(size_t)s * 128 + r * 16 + 8 + h] + a * ch;
    logit = (logit > 0.f) ? logit : NEG * logit;
    float mn = fmaxf(m, logit);
    float sc = __expf(m - mn);
    float p = __expf(logit - mn);
    float2 tv = load2(&t[((size_t)r * NN + s) * HD + 2 * tid]);
    l = l * sc + p;
    acc0 = acc0 * sc + p * tv.x;
    acc1 = acc1 * sc + p * tv.y;
    m = mn;
  }
  float inv = 1.f / (l + 1e-16f);
  float v0 = acc0 * inv, v1 = acc1 * inv;
  if (CONCAT) {
    float2 bb = *(const float2*)&bias[2 * tid];
    *(float2*)&out[(size_t)n * HD + 2 * tid] = make_float2(v0 + bb.x, v1 + bb.y);
  } else {
    __shared__ float sm[HD];
    sm[2 * tid] = v0; sm[2 * tid + 1] = v1;
    __syncthreads();
    if (tid < DOUT) {
      float s = 0.f;
#pragma unroll
      for (int hh = 0; hh < NHEAD; ++hh) s += sm[hh * DOUT + tid];
      out[(size_t)n * DOUT + tid] = s * 0.125f + bias[tid];
    }
  }
}

// ---------- launch ----------
template <typename TC>
static void run_pipeline(const float* x, const int* ei, const int* et, const float* ea,
                         const float* W1, const float* q1, const float* k1,
                         const float* We1, const float* e1, const float* b1,
                         const float* W2, const float* q2, const float* k2,
                         const float* We2, const float* e2, const float* b2,
                         float* out, float* hbuf, float* qkbuf, float* WQK,
                         unsigned short* A2, unsigned short* BT,
                         float* cvec, int* meta, int* deg, int* rowptr,
                         int* fill, int* csr_src, int* csr_et, float* csr_ea,
                         TC* t, hipStream_t stream) {
  (void)hipMemsetAsync(meta, 0, 4, stream);
  (void)hipMemsetAsync(deg, 0, (size_t)NN * 4, stream);
  k_max_et<<<EE / 256, 256, 0, stream>>>(et, meta);
  k_hist<<<(ETOT + 255) / 256, 256, 0, stream>>>(ei, deg);
  k_scan<<<1, 1024, 0, stream>>>(deg, rowptr, fill);
  k_scatter<<<(ETOT + 255) / 256, 256, 0, stream>>>(ei, et, ea, meta, fill,
                                                    csr_src, csr_et, csr_ea);
  // layer 1 (F=256, Kp=512)
  k_cvec<<<1, 64, 0, stream>>>(We1, e1, cvec);
  k_wqk<<<RREL * 256 * 16 / 256, 256, 0, stream>>>(W1, q1, k1, WQK, 256);
  k_asplit<<<(NN * 64 + 255) / 256, 256, 0, stream>>>(x, A2, 256);
  k_bsplit<<<dim3(4, 8, RREL), 256, 0, stream>>>(W1, BT, 256);
  k_mgemm<TC><<<4000, 256, 0, stream>>>(A2, BT, t, 512, (long)NN * HD);
  k_gemm<<<125, 256, 0, stream>>>(x, WQK, qkbuf, 256);
  k_attn<TC, 1><<<NN, 256, 0, stream>>>(t, qkbuf, cvec, rowptr, csr_src, csr_et,
                                        csr_ea, b1, hbuf);
  // layer 2 (F=512, Kp=1024)
  k_cvec<<<1, 64, 0, stream>>>(We2, e2, cvec);
  k_wqk<<<RREL * HD * 16 / 256, 256, 0, stream>>>(W2, q2, k2, WQK, HD);
  k_asplit<<<(NN * 128 + 255) / 256, 256, 0, stream>>>(hbuf, A2, HD);
  k_bsplit<<<dim3(8, 8, RREL), 256, 0, stream>>>(W2, BT, HD);
  k_mgemm<TC><<<4000, 256, 0, stream>>>(A2, BT, t, 1024, (long)NN * HD);
  k_gemm<<<125, 256, 0, stream>>>(hbuf, WQK, qkbuf, HD);
  k_attn<TC, 0><<<NN, 256, 0, stream>>>(t, qkbuf, cvec, rowptr, csr_src, csr_et,
                                        csr_ea, b2, out);
}

extern "C" void kernel_launch(void* const* d_in, const int* in_sizes, int n_in,
                              void* d_out, int out_size, void* d_ws, size_t ws_size,
                              hipStream_t stream) {
  const float* x   = (const float*)d_in[0];
  const int*   ei  = (const int*)d_in[1];
  const int*   et  = (const int*)d_in[2];
  const float* ea  = (const float*)d_in[3];
  const float* W1  = (const float*)d_in[4];
  const float* q1  = (const float*)d_in[5];
  const float* k1  = (const float*)d_in[6];
  const float* We1 = (const float*)d_in[7];
  const float* e1  = (const float*)d_in[8];
  const float* b1  = (const float*)d_in[9];
  const float* W2  = (const float*)d_in[10];
  const float* q2  = (const float*)d_in[11];
  const float* k2  = (const float*)d_in[12];
  const float* We2 = (const float*)d_in[13];
  const float* e2  = (const float*)d_in[14];
  const float* b2  = (const float*)d_in[15];
  float* out = (float*)d_out;

  char* w = (char*)d_ws;
  auto alloc = [&](size_t bytes) {
    char* p = w;
    w += (bytes + 255) & ~(size_t)255;
    return p;
  };
  float* hbuf   = (float*)alloc((size_t)NN * HD * 4);
  float* qkbuf  = (float*)alloc((size_t)NN * 128 * 4);
  float* WQK    = (float*)alloc((size_t)HD * 128 * 4);
  unsigned short* A2 = (unsigned short*)alloc((size_t)NN * 2 * HD * 2);
  unsigned short* BT = (unsigned short*)alloc((size_t)RREL * HD * 2 * HD * 2);
  float* cvec   = (float*)alloc(64);
  int*   meta   = (int*)alloc(64);
  int*   deg    = (int*)alloc((size_t)NN * 4);
  int*   rowptr = (int*)alloc((size_t)(NN + 1) * 4);
  int*   fill   = (int*)alloc((size_t)NN * 4);
  int*   csr_src= (int*)alloc((size_t)ETOT * 4);
  int*   csr_et = (int*)alloc((size_t)ETOT * 4);
  float* csr_ea = (float*)alloc((size_t)ETOT * 4);
  size_t used = (size_t)(w - (char*)d_ws);
  size_t t_elems = (size_t)RREL * NN * HD;

  if (used + t_elems * 4 <= ws_size) {
    float* t = (float*)w;
    run_pipeline<float>(x, ei, et, ea, W1, q1, k1, We1, e1, b1,
                        W2, q2, k2, We2, e2, b2, out, hbuf, qkbuf, WQK, A2, BT,
                        cvec, meta, deg, rowptr, fill, csr_src, csr_et, csr_ea,
                        t, stream);
  } else {
    unsigned short* t = (unsigned short*)w;
    run_pipeline<unsigned short>(x, ei, et, ea, W1, q1, k1, We1, e1, b1,
                                 W2, q2, k2, We2, e2, b2, out, hbuf, qkbuf, WQK,
                                 A2, BT, cvec, meta, deg, rowptr, fill, csr_src,
                                 csr_et, csr_ea, t, stream);
  }
}

// Round 7
// 840.355 us; speedup vs baseline: 1.0466x; 1.0466x over previous
//
#include <hip/hip_runtime.h>
#include <hip/hip_bf16.h>
#include <cstdint>
#include <cstddef>

#define NN 16000
#define MPAD 16128
#define EE 256000
#define ETOT (EE + NN)
#define RREL 8
#define NHEAD 8
#define DOUT 64
#define HD 512
#define NEG 0.2f

typedef unsigned int u32;
typedef short bf16x8 __attribute__((ext_vector_type(8)));
typedef float f32x4 __attribute__((ext_vector_type(4)));

// ---------- helpers ----------
__device__ inline unsigned short f2bf(float f) {
  u32 i = __float_as_uint(f);
  u32 r = (i + 0x7fff + ((i >> 16) & 1)) >> 16;  // RNE, finite values
  return (unsigned short)r;
}
__device__ inline float bf2f(unsigned short h) {
  return __uint_as_float((u32)h << 16);
}
__device__ inline float2 load2bf(const unsigned short* p) {
  u32 v = *(const u32*)p;
  float lo = __uint_as_float((v & 0xffffu) << 16);
  float hi = __uint_as_float(v & 0xffff0000u);
  return make_float2(lo, hi);
}
__device__ inline void g2lds16(const void* g, void* lds) {
  __builtin_amdgcn_global_load_lds(
      (const __attribute__((address_space(1))) unsigned int*)g,
      (__attribute__((address_space(3))) unsigned int*)lds, 16, 0, 0);
}

// ---------- preprocessing ----------
__global__ void k_max_et(const int* __restrict__ et, int* meta) {
  int e = blockIdx.x * 256 + threadIdx.x;
  if (e < EE) atomicMax(&meta[0], et[e]);
}

__global__ void k_hist(const int* __restrict__ ei, int* __restrict__ deg) {
  int e = blockIdx.x * 256 + threadIdx.x;
  if (e >= ETOT) return;
  int dst = (e < EE) ? ei[EE + e] : (e - EE);
  atomicAdd(&deg[dst], 1);
}

__global__ __launch_bounds__(1024) void k_scan(const int* __restrict__ deg,
                                               int* __restrict__ rowptr,
                                               int* __restrict__ fill) {
  __shared__ int sm[1024];
  __shared__ int carry;
  if (threadIdx.x == 0) carry = 0;
  __syncthreads();
  for (int base = 0; base < NN; base += 1024) {
    int i = base + threadIdx.x;
    int v = (i < NN) ? deg[i] : 0;
    sm[threadIdx.x] = v;
    __syncthreads();
    for (int off = 1; off < 1024; off <<= 1) {
      int t = (threadIdx.x >= off) ? sm[threadIdx.x - off] : 0;
      __syncthreads();
      sm[threadIdx.x] += t;
      __syncthreads();
    }
    int incl = sm[threadIdx.x] + carry;
    if (i < NN) { rowptr[i] = incl - v; fill[i] = incl - v; }
    __syncthreads();
    if (threadIdx.x == 1023) carry = incl;
    __syncthreads();
  }
  if (threadIdx.x == 0) rowptr[NN] = carry;
}

__global__ void k_scatter(const int* __restrict__ ei, const int* __restrict__ et,
                          const float* __restrict__ ea, const int* __restrict__ meta,
                          int* __restrict__ fill, int* __restrict__ csr_src,
                          int* __restrict__ csr_et, float* __restrict__ csr_ea) {
  int e = blockIdx.x * 256 + threadIdx.x;
  if (e >= ETOT) return;
  int src, dst, r; float a;
  if (e < EE) { src = ei[e]; dst = ei[EE + e]; r = et[e]; a = ea[e]; }
  else { src = dst = e - EE; r = (meta[0] + 1) & (RREL - 1); a = 0.5f; }
  int pos = atomicAdd(&fill[dst], 1);
  csr_src[pos] = src; csr_et[pos] = r; csr_ea[pos] = a;
}

// ---------- per-layer small precomputes ----------
__global__ void k_cvec(const float* __restrict__ We, const float* __restrict__ e,
                       float* __restrict__ cvec) {
  int j = threadIdx.x;
  if (j >= NHEAD) return;
  float acc = 0.f;
  for (int h = 0; h < HD; ++h) acc += We[h] * e[h * NHEAD + j];
  cvec[j] = acc;
}

// WQK[f, r*16 + j] : j<8 -> W[r,f,:]@q[:,j] ; j>=8 -> W[r,f,:]@k[:,j-8]
__global__ void k_wqk(const float* __restrict__ W, const float* __restrict__ q,
                      const float* __restrict__ k, float* __restrict__ WQK, int F) {
  int g = blockIdx.x * 256 + threadIdx.x;
  int j = g & 15;
  int rf = g >> 4;  // r*F + f
  int r = rf / F, f = rf % F;
  const float* wrow = W + (size_t)rf * HD;
  const float* qk = ((j < 8) ? q : k) + (j & 7);
  float acc = 0.f;
  for (int h = 0; h < HD; ++h) acc += wrow[h] * qk[(size_t)h * NHEAD];
  WQK[(size_t)f * 128 + r * 16 + j] = acc;
}

// ---------- split-bf16 operand builders (2-term: A=[hi|lo], B=[hi;hi]) ----
__global__ void k_asplit(const float* __restrict__ in, unsigned short* __restrict__ A2,
                         int F) {
  long idx = (long)blockIdx.x * 256 + threadIdx.x;  // over NN * F/4
  long total = (long)NN * (F >> 2);
  if (idx >= total) return;
  int row = (int)(idx / (F >> 2));
  int c4 = (int)(idx % (F >> 2)) << 2;
  float4 v = *(const float4*)&in[(size_t)row * F + c4];
  ushort4 hi, lo;
  hi.x = f2bf(v.x); hi.y = f2bf(v.y); hi.z = f2bf(v.z); hi.w = f2bf(v.w);
  lo.x = f2bf(v.x - bf2f(hi.x)); lo.y = f2bf(v.y - bf2f(hi.y));
  lo.z = f2bf(v.z - bf2f(hi.z)); lo.w = f2bf(v.w - bf2f(hi.w));
  unsigned short* base = A2 + (size_t)row * 2 * F;
  *(ushort4*)&base[c4] = hi;
  *(ushort4*)&base[F + c4] = lo;
}

// W: [R][F][512] f32 -> BT: flattened [4096 cols][2F] bf16 (col-major B),
// BT[(r*512+c)][k'] = hi of W[r][k'%F][c]
__global__ __launch_bounds__(256) void k_bsplit(const float* __restrict__ W,
                                                unsigned short* __restrict__ BT, int F) {
  int f0 = blockIdx.x * 64, c0 = blockIdx.y * 64, r = blockIdx.z;
  __shared__ float tile[64][65];
  int tid = threadIdx.x;
  int i0 = tid >> 6;   // 0..3
  int j = tid & 63;
  const float* Wr = W + (size_t)r * F * 512;
  for (int i = i0; i < 64; i += 4)
    tile[i][j] = Wr[(size_t)(f0 + i) * 512 + c0 + j];
  __syncthreads();
  unsigned short* Br = BT + (size_t)r * 512 * 2 * F;
  for (int c = i0; c < 64; c += 4) {
    float v = tile[j][c];  // W[r][f0+j][c0+c]
    unsigned short hi = f2bf(v);
    unsigned short* dst = Br + (size_t)(c0 + c) * 2 * F + f0 + j;
    dst[0] = hi; dst[F] = hi;
  }
}

// ---------- MFMA GEMM: C = A2[16128 x Kp] @ BT^T  (N = 4096 flattened) ----
// BM=256, BN=128, BK=64, 8 waves (4m x 2n, each 64x64), 3 LDS buffers
// (144 KB), depth-2 prefetch with counted vmcnt(6), raw s_barrier, setprio
// around the MFMA cluster. Fragment-linear LDS: gload_lds writes in exact
// fragment order (wave-uniform dst + lane*16B), ds_read_b128 lane-linear ->
// conflict-free without swizzle. C written as t[r][row][h] (r=col>>9).
__global__ __launch_bounds__(512, 2) void k_mgemm(const unsigned short* __restrict__ A2,
                                                  const unsigned short* __restrict__ BT,
                                                  unsigned short* __restrict__ Ct,
                                                  int Kp) {
  const int bid = blockIdx.x;
  const int v = (bid & 7) * 252 + (bid >> 3);   // 2016 = 8*252, bijective
  const int mb = v >> 5;                        // 0..62 (m-panel slow)
  const int nb = v & 31;                        // n fastest: A panel L2-shared
  const int m0 = mb << 8;
  const int n0 = nb << 7;

  __shared__ __align__(16) unsigned short smem[3 * 16384 + 3 * 8192];  // 144 KB
  unsigned short* Asm = smem;                   // [3][16384]
  unsigned short* Bsm = smem + 3 * 16384;       // [3][8192]

  const int tid = threadIdx.x;
  const int wid = tid >> 6;
  const int lane = tid & 63;
  const int wr = wid >> 1;     // 0..3 (m)
  const int wc = wid & 1;      // 0..1 (n)
  const int rlow = lane & 15;
  const int kch = lane >> 4;   // 0..3

  // staging: per wave 4 A-groups + 2 B-groups of 1 KB each
  const unsigned short* srcA[4];
  int dstA[4];
#pragma unroll
  for (int p = 0; p < 4; ++p) {
    int ga = wid * 4 + p;        // 0..31
    int kk = ga >> 4, gm = ga & 15;
    srcA[p] = A2 + (size_t)(m0 + gm * 16 + rlow) * Kp + kk * 32 + kch * 8;
    dstA[p] = kk * 8192 + gm * 512;
  }
  const unsigned short* srcB[2];
  int dstB[2];
#pragma unroll
  for (int p = 0; p < 2; ++p) {
    int gb = wid * 2 + p;        // 0..15
    int kk = gb >> 3, gn = gb & 7;
    srcB[p] = BT + (size_t)(n0 + gn * 16 + rlow) * Kp + kk * 32 + kch * 8;
    dstB[p] = kk * 4096 + gn * 512;
  }

  f32x4 acc[4][4] = {};
  const int nt = Kp >> 6;

  // prologue: stage tiles 0,1 into buffers 0,1 (12 vm-ops per wave)
  for (int tp = 0; tp < 2 && tp < nt; ++tp) {
    int ko = tp << 6;
#pragma unroll
    for (int p = 0; p < 4; ++p) g2lds16(srcA[p] + ko, &Asm[tp * 16384 + dstA[p]]);
#pragma unroll
    for (int p = 0; p < 2; ++p) g2lds16(srcB[p] + ko, &Bsm[tp * 8192 + dstB[p]]);
  }

  int buf = 0;
  for (int t = 0; t < nt; ++t) {
    if (t + 1 < nt) {
      asm volatile("s_waitcnt vmcnt(6)" ::: "memory");
    } else {
      asm volatile("s_waitcnt vmcnt(0)" ::: "memory");
    }
    __builtin_amdgcn_s_barrier();
    asm volatile("" ::: "memory");
    if (t + 2 < nt) {
      int nbuf = buf + 2; if (nbuf >= 3) nbuf -= 3;
      int ko = (t + 2) << 6;
#pragma unroll
      for (int p = 0; p < 4; ++p) g2lds16(srcA[p] + ko, &Asm[nbuf * 16384 + dstA[p]]);
#pragma unroll
      for (int p = 0; p < 2; ++p) g2lds16(srcB[p] + ko, &Bsm[nbuf * 8192 + dstB[p]]);
    }
    bf16x8 af[2][4], bfr[2][4];
#pragma unroll
    for (int kk = 0; kk < 2; ++kk) {
#pragma unroll
      for (int i = 0; i < 4; ++i)
        af[kk][i] = *(const bf16x8*)&Asm[buf * 16384 + kk * 8192 + (wr * 4 + i) * 512 + lane * 8];
#pragma unroll
      for (int j = 0; j < 4; ++j)
        bfr[kk][j] = *(const bf16x8*)&Bsm[buf * 8192 + kk * 4096 + (wc * 4 + j) * 512 + lane * 8];
    }
    __builtin_amdgcn_s_setprio(1);
#pragma unroll
    for (int kk = 0; kk < 2; ++kk)
#pragma unroll
      for (int i = 0; i < 4; ++i)
#pragma unroll
        for (int j = 0; j < 4; ++j)
          acc[i][j] = __builtin_amdgcn_mfma_f32_16x16x32_bf16(af[kk][i], bfr[kk][j],
                                                              acc[i][j], 0, 0, 0);
    __builtin_amdgcn_s_setprio(0);
    buf = (buf == 2) ? 0 : buf + 1;
  }

  // ---- epilogue: LDS transpose, 4 passes of 64 rows, coalesced stores ----
  __syncthreads();
  float* eps = (float*)smem;          // [128 cols][68]
  const int row = tid >> 3;           // 0..63
  const int cg = (tid & 7) * 16;      // 0..112
#pragma unroll 1
  for (int p = 0; p < 4; ++p) {
    if (p) __syncthreads();
    if (wr == p) {
#pragma unroll
      for (int i = 0; i < 4; ++i)
#pragma unroll
        for (int j = 0; j < 4; ++j)
          *(f32x4*)&eps[(wc * 64 + j * 16 + rlow) * 68 + i * 16 + kch * 4] = acc[i][j];
    }
    __syncthreads();
    float vals[16];
#pragma unroll
    for (int c = 0; c < 16; ++c) vals[c] = eps[(cg + c) * 68 + row];
    const int colg = n0 + cg;
    const int rr = colg >> 9;
    const int h = colg & 511;
    unsigned short* dst = Ct + ((size_t)rr * MPAD + (m0 + p * 64 + row)) * HD + h;
    uint4 w0, w1;
    w0.x = (u32)f2bf(vals[0])  | ((u32)f2bf(vals[1])  << 16);
    w0.y = (u32)f2bf(vals[2])  | ((u32)f2bf(vals[3])  << 16);
    w0.z = (u32)f2bf(vals[4])  | ((u32)f2bf(vals[5])  << 16);
    w0.w = (u32)f2bf(vals[6])  | ((u32)f2bf(vals[7])  << 16);
    w1.x = (u32)f2bf(vals[8])  | ((u32)f2bf(vals[9])  << 16);
    w1.y = (u32)f2bf(vals[10]) | ((u32)f2bf(vals[11]) << 16);
    w1.z = (u32)f2bf(vals[12]) | ((u32)f2bf(vals[13]) << 16);
    w1.w = (u32)f2bf(vals[14]) | ((u32)f2bf(vals[15]) << 16);
    *(uint4*)dst = w0;
    *(uint4*)(dst + 8) = w1;
  }
}

// ---------- small fp32 GEMM (for qkbuf): C = A @ B, B:[F][128] ----------
__global__ __launch_bounds__(256) void k_gemm(const float* __restrict__ A,
                                              const float* __restrict__ B,
                                              float* __restrict__ C, int F) {
  const int m0 = blockIdx.x * 128;
  __shared__ float As[16][132];
  __shared__ float Bs[16][132];
  const int tid = threadIdx.x;
  const int arow = tid >> 2;
  const int acol = (tid & 3) << 2;
  const int brow = tid >> 5;
  const int bcol = (tid & 31) << 2;
  const int tr = ((tid >> 4) & 15) << 2;
  const int tc = (tid & 15) << 2;
  float acc[8][8] = {};
  for (int k0 = 0; k0 < F; k0 += 16) {
    float4 a0 = *(const float4*)&A[(size_t)(m0 + arow) * F + k0 + acol];
    float4 a1 = *(const float4*)&A[(size_t)(m0 + arow + 64) * F + k0 + acol];
    float4 b0 = *(const float4*)&B[(size_t)(k0 + brow) * 128 + bcol];
    float4 b1 = *(const float4*)&B[(size_t)(k0 + brow + 8) * 128 + bcol];
    As[acol + 0][arow] = a0.x; As[acol + 1][arow] = a0.y;
    As[acol + 2][arow] = a0.z; As[acol + 3][arow] = a0.w;
    As[acol + 0][arow + 64] = a1.x; As[acol + 1][arow + 64] = a1.y;
    As[acol + 2][arow + 64] = a1.z; As[acol + 3][arow + 64] = a1.w;
    *(float4*)&Bs[brow][bcol] = b0;
    *(float4*)&Bs[brow + 8][bcol] = b1;
    __syncthreads();
#pragma unroll
    for (int k = 0; k < 16; ++k) {
      float a[8], b[8];
      *(float4*)(a) = *(const float4*)&As[k][tr];
      *(float4*)(a + 4) = *(const float4*)&As[k][tr + 64];
      *(float4*)(b) = *(const float4*)&Bs[k][tc];
      *(float4*)(b + 4) = *(const float4*)&Bs[k][tc + 64];
#pragma unroll
      for (int i = 0; i < 8; ++i)
#pragma unroll
        for (int j = 0; j < 8; ++j)
          acc[i][j] = fmaf(a[i], b[j], acc[i][j]);
    }
    __syncthreads();
  }
#pragma unroll
  for (int i = 0; i < 8; ++i) {
    int row = m0 + tr + ((i < 4) ? i : (60 + i));
    *(float4*)&C[(size_t)row * 128 + tc] = make_float4(acc[i][0], acc[i][1], acc[i][2], acc[i][3]);
    *(float4*)&C[(size_t)row * 128 + tc + 64] = make_float4(acc[i][4], acc[i][5], acc[i][6], acc[i][7]);
  }
}

// ---------- fused attention + aggregation, one block per dst node ----------
template <int CONCAT>
__global__ __launch_bounds__(256) void k_attn(const unsigned short* __restrict__ t,
    const float* __restrict__ qkbuf, const float* __restrict__ cvec,
    const int* __restrict__ rowptr, const int* __restrict__ csr_src,
    const int* __restrict__ csr_et, const float* __restrict__ csr_ea,
    const float* __restrict__ bias, float* __restrict__ out) {
  const int n = blockIdx.x;
  const int tid = threadIdx.x;
  const int h = tid >> 5;  // head of elements 2*tid, 2*tid+1
  const int e0 = rowptr[n], e1 = rowptr[n + 1];
  const float ch = cvec[h];
  const float* qrow = qkbuf + (size_t)n * 128;
  float m = -1e30f, l = 0.f, acc0 = 0.f, acc1 = 0.f;
  for (int e = e0; e < e1; ++e) {
    int s = csr_src[e];
    int r = csr_et[e];
    float a = csr_ea[e];
    float logit = qrow[r * 16 + h]
                + qkbuf[(size_t)s * 128 + r * 16 + 8 + h] + a * ch;
    logit = (logit > 0.f) ? logit : NEG * logit;
    float mn = fmaxf(m, logit);
    float sc = __expf(m - mn);
    float p = __expf(logit - mn);
    float2 tv = load2bf(&t[((size_t)r * MPAD + s) * HD + 2 * tid]);
    l = l * sc + p;
    acc0 = acc0 * sc + p * tv.x;
    acc1 = acc1 * sc + p * tv.y;
    m = mn;
  }
  float inv = 1.f / (l + 1e-16f);
  float v0 = acc0 * inv, v1 = acc1 * inv;
  if (CONCAT) {
    float2 bb = *(const float2*)&bias[2 * tid];
    *(float2*)&out[(size_t)n * HD + 2 * tid] = make_float2(v0 + bb.x, v1 + bb.y);
  } else {
    __shared__ float sm[HD];
    sm[2 * tid] = v0; sm[2 * tid + 1] = v1;
    __syncthreads();
    if (tid < DOUT) {
      float s = 0.f;
#pragma unroll
      for (int hh = 0; hh < NHEAD; ++hh) s += sm[hh * DOUT + tid];
      out[(size_t)n * DOUT + tid] = s * 0.125f + bias[tid];
    }
  }
}

// ---------- launch ----------
static void run_pipeline(const float* x, const int* ei, const int* et, const float* ea,
                         const float* W1, const float* q1, const float* k1,
                         const float* We1, const float* e1, const float* b1,
                         const float* W2, const float* q2, const float* k2,
                         const float* We2, const float* e2, const float* b2,
                         float* out, float* hbuf, float* qkbuf, float* WQK,
                         unsigned short* A2, unsigned short* BT,
                         float* cvec, int* meta, int* deg, int* rowptr,
                         int* fill, int* csr_src, int* csr_et, float* csr_ea,
                         unsigned short* t, hipStream_t stream) {
  (void)hipMemsetAsync(meta, 0, 4, stream);
  (void)hipMemsetAsync(deg, 0, (size_t)NN * 4, stream);
  k_max_et<<<EE / 256, 256, 0, stream>>>(et, meta);
  k_hist<<<(ETOT + 255) / 256, 256, 0, stream>>>(ei, deg);
  k_scan<<<1, 1024, 0, stream>>>(deg, rowptr, fill);
  k_scatter<<<(ETOT + 255) / 256, 256, 0, stream>>>(ei, et, ea, meta, fill,
                                                    csr_src, csr_et, csr_ea);
  // layer 1 (F=256, Kp=512)
  k_cvec<<<1, 64, 0, stream>>>(We1, e1, cvec);
  k_wqk<<<RREL * 256 * 16 / 256, 256, 0, stream>>>(W1, q1, k1, WQK, 256);
  k_asplit<<<(NN * 64 + 255) / 256, 256, 0, stream>>>(x, A2, 256);
  k_bsplit<<<dim3(4, 8, RREL), 256, 0, stream>>>(W1, BT, 256);
  k_mgemm<<<2016, 512, 0, stream>>>(A2, BT, t, 512);
  k_gemm<<<125, 256, 0, stream>>>(x, WQK, qkbuf, 256);
  k_attn<1><<<NN, 256, 0, stream>>>(t, qkbuf, cvec, rowptr, csr_src, csr_et,
                                    csr_ea, b1, hbuf);
  // layer 2 (F=512, Kp=1024)
  k_cvec<<<1, 64, 0, stream>>>(We2, e2, cvec);
  k_wqk<<<RREL * HD * 16 / 256, 256, 0, stream>>>(W2, q2, k2, WQK, HD);
  k_asplit<<<(NN * 128 + 255) / 256, 256, 0, stream>>>(hbuf, A2, HD);
  k_bsplit<<<dim3(8, 8, RREL), 256, 0, stream>>>(W2, BT, HD);
  k_mgemm<<<2016, 512, 0, stream>>>(A2, BT, t, 1024);
  k_gemm<<<125, 256, 0, stream>>>(hbuf, WQK, qkbuf, HD);
  k_attn<0><<<NN, 256, 0, stream>>>(t, qkbuf, cvec, rowptr, csr_src, csr_et,
                                    csr_ea, b2, out);
}

extern "C" void kernel_launch(void* const* d_in, const int* in_sizes, int n_in,
                              void* d_out, int out_size, void* d_ws, size_t ws_size,
                              hipStream_t stream) {
  const float* x   = (const float*)d_in[0];
  const int*   ei  = (const int*)d_in[1];
  const int*   et  = (const int*)d_in[2];
  const float* ea  = (const float*)d_in[3];
  const float* W1  = (const float*)d_in[4];
  const float* q1  = (const float*)d_in[5];
  const float* k1  = (const float*)d_in[6];
  const float* We1 = (const float*)d_in[7];
  const float* e1  = (const float*)d_in[8];
  const float* b1  = (const float*)d_in[9];
  const float* W2  = (const float*)d_in[10];
  const float* q2  = (const float*)d_in[11];
  const float* k2  = (const float*)d_in[12];
  const float* We2 = (const float*)d_in[13];
  const float* e2  = (const float*)d_in[14];
  const float* b2  = (const float*)d_in[15];
  float* out = (float*)d_out;

  char* w = (char*)d_ws;
  auto alloc = [&](size_t bytes) {
    char* p = w;
    w += (bytes + 255) & ~(size_t)255;
    return p;
  };
  float* hbuf   = (float*)alloc((size_t)NN * HD * 4);
  float* qkbuf  = (float*)alloc((size_t)NN * 128 * 4);
  float* WQK    = (float*)alloc((size_t)HD * 128 * 4);
  unsigned short* A2 = (unsigned short*)alloc((size_t)MPAD * 2 * HD * 2);
  unsigned short* BT = (unsigned short*)alloc((size_t)RREL * HD * 2 * HD * 2);
  float* cvec   = (float*)alloc(64);
  int*   meta   = (int*)alloc(64);
  int*   deg    = (int*)alloc((size_t)NN * 4);
  int*   rowptr = (int*)alloc((size_t)(NN + 1) * 4);
  int*   fill   = (int*)alloc((size_t)NN * 4);
  int*   csr_src= (int*)alloc((size_t)ETOT * 4);
  int*   csr_et = (int*)alloc((size_t)ETOT * 4);
  float* csr_ea = (float*)alloc((size_t)ETOT * 4);
  unsigned short* t = (unsigned short*)alloc((size_t)RREL * MPAD * HD * 2);
  (void)ws_size;

  run_pipeline(x, ei, et, ea, W1, q1, k1, We1, e1, b1,
               W2, q2, k2, We2, e2, b2, out, hbuf, qkbuf, WQK, A2, BT,
               cvec, meta, deg, rowptr, fill, csr_src, csr_et, csr_ea,
               t, stream);
}

// Round 8
// 774.350 us; speedup vs baseline: 1.1358x; 1.0852x over previous
//
#include <hip/hip_runtime.h>
#include <hip/hip_bf16.h>
#include <cstdint>
#include <cstddef>

#define NN 16000
#define MPAD 16128
#define EE 256000
#define ETOT (EE + NN)
#define RREL 8
#define NHEAD 8
#define DOUT 64
#define HD 512
#define NEG 0.2f

typedef unsigned int u32;
typedef short bf16x8 __attribute__((ext_vector_type(8)));
typedef float f32x4 __attribute__((ext_vector_type(4)));

// ---------- helpers ----------
__device__ inline unsigned short f2bf(float f) {
  u32 i = __float_as_uint(f);
  u32 r = (i + 0x7fff + ((i >> 16) & 1)) >> 16;  // RNE, finite values
  return (unsigned short)r;
}
__device__ inline float bf2f(unsigned short h) {
  return __uint_as_float((u32)h << 16);
}
__device__ inline float2 load2bf(const unsigned short* p) {
  u32 v = *(const u32*)p;
  float lo = __uint_as_float((v & 0xffffu) << 16);
  float hi = __uint_as_float(v & 0xffff0000u);
  return make_float2(lo, hi);
}
__device__ inline void g2lds16(const void* g, void* lds) {
  __builtin_amdgcn_global_load_lds(
      (const __attribute__((address_space(1))) unsigned int*)g,
      (__attribute__((address_space(3))) unsigned int*)lds, 16, 0, 0);
}

// ---------- preprocessing ----------
__global__ void k_max_et(const int* __restrict__ et, int* meta) {
  int e = blockIdx.x * 256 + threadIdx.x;
  if (e < EE) atomicMax(&meta[0], et[e]);
}

__global__ void k_hist(const int* __restrict__ ei, int* __restrict__ deg) {
  int e = blockIdx.x * 256 + threadIdx.x;
  if (e >= ETOT) return;
  int dst = (e < EE) ? ei[EE + e] : (e - EE);
  atomicAdd(&deg[dst], 1);
}

__global__ __launch_bounds__(1024) void k_scan(const int* __restrict__ deg,
                                               int* __restrict__ rowptr,
                                               int* __restrict__ fill) {
  __shared__ int sm[1024];
  __shared__ int carry;
  if (threadIdx.x == 0) carry = 0;
  __syncthreads();
  for (int base = 0; base < NN; base += 1024) {
    int i = base + threadIdx.x;
    int v = (i < NN) ? deg[i] : 0;
    sm[threadIdx.x] = v;
    __syncthreads();
    for (int off = 1; off < 1024; off <<= 1) {
      int t = (threadIdx.x >= off) ? sm[threadIdx.x - off] : 0;
      __syncthreads();
      sm[threadIdx.x] += t;
      __syncthreads();
    }
    int incl = sm[threadIdx.x] + carry;
    if (i < NN) { rowptr[i] = incl - v; fill[i] = incl - v; }
    __syncthreads();
    if (threadIdx.x == 1023) carry = incl;
    __syncthreads();
  }
  if (threadIdx.x == 0) rowptr[NN] = carry;
}

__global__ void k_scatter(const int* __restrict__ ei, const int* __restrict__ et,
                          const float* __restrict__ ea, const int* __restrict__ meta,
                          int* __restrict__ fill, int* __restrict__ csr_src,
                          int* __restrict__ csr_et, float* __restrict__ csr_ea) {
  int e = blockIdx.x * 256 + threadIdx.x;
  if (e >= ETOT) return;
  int src, dst, r; float a;
  if (e < EE) { src = ei[e]; dst = ei[EE + e]; r = et[e]; a = ea[e]; }
  else { src = dst = e - EE; r = (meta[0] + 1) & (RREL - 1); a = 0.5f; }
  int pos = atomicAdd(&fill[dst], 1);
  csr_src[pos] = src; csr_et[pos] = r; csr_ea[pos] = a;
}

// ---------- per-layer small precomputes ----------
__global__ void k_cvec(const float* __restrict__ We, const float* __restrict__ e,
                       float* __restrict__ cvec) {
  int j = threadIdx.x;
  if (j >= NHEAD) return;
  float acc = 0.f;
  for (int h = 0; h < HD; ++h) acc += We[h] * e[h * NHEAD + j];
  cvec[j] = acc;
}

// WQK[f, r*16 + j] : j<8 -> W[r,f,:]@q[:,j] ; j>=8 -> W[r,f,:]@k[:,j-8]
__global__ void k_wqk(const float* __restrict__ W, const float* __restrict__ q,
                      const float* __restrict__ k, float* __restrict__ WQK, int F) {
  int g = blockIdx.x * 256 + threadIdx.x;
  int j = g & 15;
  int rf = g >> 4;  // r*F + f
  int r = rf / F, f = rf % F;
  const float* wrow = W + (size_t)rf * HD;
  const float* qk = ((j < 8) ? q : k) + (j & 7);
  float acc = 0.f;
  for (int h = 0; h < HD; ++h) acc += wrow[h] * qk[(size_t)h * NHEAD];
  WQK[(size_t)f * 128 + r * 16 + j] = acc;
}

// ---------- split-bf16 operand builders (2-term: A=[hi|lo], B=[hi;hi]) ----
__global__ void k_asplit(const float* __restrict__ in, unsigned short* __restrict__ A2,
                         int F) {
  long idx = (long)blockIdx.x * 256 + threadIdx.x;  // over NN * F/4
  long total = (long)NN * (F >> 2);
  if (idx >= total) return;
  int row = (int)(idx / (F >> 2));
  int c4 = (int)(idx % (F >> 2)) << 2;
  float4 v = *(const float4*)&in[(size_t)row * F + c4];
  ushort4 hi, lo;
  hi.x = f2bf(v.x); hi.y = f2bf(v.y); hi.z = f2bf(v.z); hi.w = f2bf(v.w);
  lo.x = f2bf(v.x - bf2f(hi.x)); lo.y = f2bf(v.y - bf2f(hi.y));
  lo.z = f2bf(v.z - bf2f(hi.z)); lo.w = f2bf(v.w - bf2f(hi.w));
  unsigned short* base = A2 + (size_t)row * 2 * F;
  *(ushort4*)&base[c4] = hi;
  *(ushort4*)&base[F + c4] = lo;
}

// W: [R][F][512] f32 -> BT: flattened [4096 cols][2F] bf16 (col-major B)
__global__ __launch_bounds__(256) void k_bsplit(const float* __restrict__ W,
                                                unsigned short* __restrict__ BT, int F) {
  int f0 = blockIdx.x * 64, c0 = blockIdx.y * 64, r = blockIdx.z;
  __shared__ float tile[64][65];
  int tid = threadIdx.x;
  int i0 = tid >> 6;   // 0..3
  int j = tid & 63;
  const float* Wr = W + (size_t)r * F * 512;
  for (int i = i0; i < 64; i += 4)
    tile[i][j] = Wr[(size_t)(f0 + i) * 512 + c0 + j];
  __syncthreads();
  unsigned short* Br = BT + (size_t)r * 512 * 2 * F;
  for (int c = i0; c < 64; c += 4) {
    float v = tile[j][c];  // W[r][f0+j][c0+c]
    unsigned short hi = f2bf(v);
    unsigned short* dst = Br + (size_t)(c0 + c) * 2 * F + f0 + j;
    dst[0] = hi; dst[F] = hi;
  }
}

// ---------- MFMA GEMM: C = A2[16128 x Kp] @ BT^T (N=4096 flat) ----------
// BM=BN=256, BK=64, 8 waves (2M x 4N, 128x64 each), 2 LDS buffers (128 KB),
// classic double-buffer: per K-tile one vmcnt(0)+barrier (loads had a full
// iteration in flight), then stage next tile, 24 ds_read_b128, 64 MFMA.
// Fragment-ordered LDS -> conflict-free ds_read. Per-wave private epilogue
// transpose (no cross-wave sync, <=2-way banks).
__global__ __launch_bounds__(512, 2) void k_mgemm(const unsigned short* __restrict__ A2,
                                                  const unsigned short* __restrict__ BT,
                                                  unsigned short* __restrict__ Ct,
                                                  int Kp) {
  const int bid = blockIdx.x;
  const int v = (bid & 7) * 126 + (bid >> 3);   // 1008 = 8*126, bijective
  const int mb = v >> 4;                        // 0..62 (m slow)
  const int nb = v & 15;                        // n fastest: A-panel L2-reuse
  const int m0 = mb << 8;
  const int n0 = nb << 8;

  __shared__ __align__(16) unsigned short smem[65536];  // 128 KB
  // A: [buf][kk][mfrag][512 shorts] at smem[buf*16384 + kk*8192 + mfrag*512]
  // B: same at +32768

  const int tid = threadIdx.x;
  const int wid = tid >> 6;
  const int lane = tid & 63;
  const int wr = wid >> 2;     // 0..1 (m half)
  const int wc = wid & 3;      // 0..3 (n quarter)
  const int rlow = lane & 15;
  const int kch = lane >> 4;   // 0..3

  // per-thread stage sources: p=0..3 -> (kk=p>>1, frag=(p&1)*8+wid)
  const unsigned short* srcA[4];
  const unsigned short* srcB[4];
  int dstOff[4];
#pragma unroll
  for (int p = 0; p < 4; ++p) {
    int kk = p >> 1, fr = ((p & 1) << 3) + wid;
    srcA[p] = A2 + (size_t)(m0 + fr * 16 + rlow) * Kp + kk * 32 + kch * 8;
    srcB[p] = BT + (size_t)(n0 + fr * 16 + rlow) * Kp + kk * 32 + kch * 8;
    dstOff[p] = kk * 8192 + fr * 512;
  }

  f32x4 acc[8][4] = {};
  const int nt = Kp >> 6;

  // prologue: stage K-tile 0 into buffer 0
#pragma unroll
  for (int p = 0; p < 4; ++p) {
    g2lds16(srcA[p], &smem[dstOff[p]]);
    g2lds16(srcB[p], &smem[32768 + dstOff[p]]);
  }

  for (int u = 0; u < nt; ++u) {
    asm volatile("s_waitcnt vmcnt(0)" ::: "memory");
    __builtin_amdgcn_s_barrier();
    asm volatile("" ::: "memory");
    const int buf = u & 1;
    if (u + 1 < nt) {
      const int ko = (u + 1) << 6;
      const int bo = (buf ^ 1) * 16384;
#pragma unroll
      for (int p = 0; p < 4; ++p) {
        g2lds16(srcA[p] + ko, &smem[bo + dstOff[p]]);
        g2lds16(srcB[p] + ko, &smem[32768 + bo + dstOff[p]]);
      }
    }
    const unsigned short* Ab = smem + buf * 16384;
    const unsigned short* Bb = smem + 32768 + buf * 16384;
#pragma unroll
    for (int kk = 0; kk < 2; ++kk) {
      bf16x8 af[8], bfv[4];
#pragma unroll
      for (int i = 0; i < 8; ++i)
        af[i] = *(const bf16x8*)&Ab[kk * 8192 + (wr * 8 + i) * 512 + lane * 8];
#pragma unroll
      for (int j = 0; j < 4; ++j)
        bfv[j] = *(const bf16x8*)&Bb[kk * 8192 + (wc * 4 + j) * 512 + lane * 8];
      __builtin_amdgcn_s_setprio(1);
#pragma unroll
      for (int i = 0; i < 8; ++i)
#pragma unroll
        for (int j = 0; j < 4; ++j)
          acc[i][j] = __builtin_amdgcn_mfma_f32_16x16x32_bf16(af[i], bfv[j],
                                                              acc[i][j], 0, 0, 0);
      __builtin_amdgcn_s_setprio(0);
    }
  }

  // ---- epilogue: per-wave private LDS transpose (no cross-wave sync) ----
  __syncthreads();  // everyone done reading buffers before reuse
  float* epsW = (float*)smem + wid * 1344;  // 64 cols x 21 pad = 5376 B/wave
  const int rowL = lane & 15;
  const int cseg = lane >> 4;               // 0..3 (16-col segment)
  const int colfull0 = n0 + wc * 64;
  const int rr = colfull0 >> 9;
  const int hbase = (colfull0 & 511) + cseg * 16;
#pragma unroll
  for (int i = 0; i < 8; ++i) {
#pragma unroll
    for (int j = 0; j < 4; ++j)
      *(f32x4*)&epsW[(j * 16 + rlow) * 21 + kch * 4] = acc[i][j];
    float vals[16];
#pragma unroll
    for (int c = 0; c < 16; ++c) vals[c] = epsW[(cseg * 16 + c) * 21 + rowL];
    const int rowg = m0 + wr * 128 + i * 16 + rowL;
    unsigned short* dst = Ct + ((size_t)rr * MPAD + rowg) * HD + hbase;
    uint4 w0, w1;
    w0.x = (u32)f2bf(vals[0])  | ((u32)f2bf(vals[1])  << 16);
    w0.y = (u32)f2bf(vals[2])  | ((u32)f2bf(vals[3])  << 16);
    w0.z = (u32)f2bf(vals[4])  | ((u32)f2bf(vals[5])  << 16);
    w0.w = (u32)f2bf(vals[6])  | ((u32)f2bf(vals[7])  << 16);
    w1.x = (u32)f2bf(vals[8])  | ((u32)f2bf(vals[9])  << 16);
    w1.y = (u32)f2bf(vals[10]) | ((u32)f2bf(vals[11]) << 16);
    w1.z = (u32)f2bf(vals[12]) | ((u32)f2bf(vals[13]) << 16);
    w1.w = (u32)f2bf(vals[14]) | ((u32)f2bf(vals[15]) << 16);
    *(uint4*)dst = w0;
    *(uint4*)(dst + 8) = w1;
    // same-wave LDS reuse across i: no barrier needed (lgkm ordering)
  }
}

// ---------- small fp32 GEMM (for qkbuf): C = A @ B, B:[F][128] ----------
__global__ __launch_bounds__(256) void k_gemm(const float* __restrict__ A,
                                              const float* __restrict__ B,
                                              float* __restrict__ C, int F) {
  const int m0 = blockIdx.x * 128;
  __shared__ float As[16][132];
  __shared__ float Bs[16][132];
  const int tid = threadIdx.x;
  const int arow = tid >> 2;
  const int acol = (tid & 3) << 2;
  const int brow = tid >> 5;
  const int bcol = (tid & 31) << 2;
  const int tr = ((tid >> 4) & 15) << 2;
  const int tc = (tid & 15) << 2;
  float acc[8][8] = {};
  for (int k0 = 0; k0 < F; k0 += 16) {
    float4 a0 = *(const float4*)&A[(size_t)(m0 + arow) * F + k0 + acol];
    float4 a1 = *(const float4*)&A[(size_t)(m0 + arow + 64) * F + k0 + acol];
    float4 b0 = *(const float4*)&B[(size_t)(k0 + brow) * 128 + bcol];
    float4 b1 = *(const float4*)&B[(size_t)(k0 + brow + 8) * 128 + bcol];
    As[acol + 0][arow] = a0.x; As[acol + 1][arow] = a0.y;
    As[acol + 2][arow] = a0.z; As[acol + 3][arow] = a0.w;
    As[acol + 0][arow + 64] = a1.x; As[acol + 1][arow + 64] = a1.y;
    As[acol + 2][arow + 64] = a1.z; As[acol + 3][arow + 64] = a1.w;
    *(float4*)&Bs[brow][bcol] = b0;
    *(float4*)&Bs[brow + 8][bcol] = b1;
    __syncthreads();
#pragma unroll
    for (int k = 0; k < 16; ++k) {
      float a[8], b[8];
      *(float4*)(a) = *(const float4*)&As[k][tr];
      *(float4*)(a + 4) = *(const float4*)&As[k][tr + 64];
      *(float4*)(b) = *(const float4*)&Bs[k][tc];
      *(float4*)(b + 4) = *(const float4*)&Bs[k][tc + 64];
#pragma unroll
      for (int i = 0; i < 8; ++i)
#pragma unroll
        for (int j = 0; j < 8; ++j)
          acc[i][j] = fmaf(a[i], b[j], acc[i][j]);
    }
    __syncthreads();
  }
#pragma unroll
  for (int i = 0; i < 8; ++i) {
    int row = m0 + tr + ((i < 4) ? i : (60 + i));
    *(float4*)&C[(size_t)row * 128 + tc] = make_float4(acc[i][0], acc[i][1], acc[i][2], acc[i][3]);
    *(float4*)&C[(size_t)row * 128 + tc + 64] = make_float4(acc[i][4], acc[i][5], acc[i][6], acc[i][7]);
  }
}

// ---------- fused attention: two-pass block softmax, one block/node ------
template <int CONCAT>
__global__ __launch_bounds__(256) void k_attn(const unsigned short* __restrict__ t,
    const float* __restrict__ qkbuf, const float* __restrict__ cvec,
    const int* __restrict__ rowptr, const int* __restrict__ csr_src,
    const int* __restrict__ csr_et, const float* __restrict__ csr_ea,
    const float* __restrict__ bias, float* __restrict__ out) {
  __shared__ float slog[256 * NHEAD];  // 8 KB: chunk logits -> p values
  __shared__ float smh[NHEAD], ssh[NHEAD];
  const int n = blockIdx.x;
  const int tid = threadIdx.x;
  const int h2 = tid >> 5;             // head of cols 2*tid, 2*tid+1
  const int lane32 = tid & 31;
  const int e0 = rowptr[n], e1 = rowptr[n + 1];
  const float* qrow = qkbuf + (size_t)n * 128;

  float macc = -1e30f, lacc = 0.f, acc0 = 0.f, acc1 = 0.f;

  for (int base = e0; base < e1; base += 256) {
    const int cnt = min(256, e1 - base);
    // pass 1a: logits (parallel over (edge, head))
    for (int it = tid; it < cnt * NHEAD; it += 256) {
      int el = it >> 3, h = it & 7;
      int e = base + el;
      int s = csr_src[e];
      int r = csr_et[e];
      float a = csr_ea[e];
      float logit = qrow[r * 16 + h] + qkbuf[(size_t)s * 128 + r * 16 + 8 + h]
                  + a * cvec[h];
      slog[el * 8 + h] = (logit > 0.f) ? logit : NEG * logit;
    }
    __syncthreads();
    // pass 1b: per-head max, then exp + sum (32 lanes per head)
    {
      float lm = -1e30f;
      for (int j = lane32; j < cnt; j += 32) lm = fmaxf(lm, slog[j * 8 + h2]);
#pragma unroll
      for (int off = 16; off; off >>= 1) lm = fmaxf(lm, __shfl_xor(lm, off, 32));
      float lsum = 0.f;
      for (int j = lane32; j < cnt; j += 32) {
        float p = __expf(slog[j * 8 + h2] - lm);
        slog[j * 8 + h2] = p;
        lsum += p;
      }
#pragma unroll
      for (int off = 16; off; off >>= 1) lsum += __shfl_xor(lsum, off, 32);
      if (lane32 == 0) { smh[h2] = lm; ssh[h2] = lsum; }
    }
    __syncthreads();
    // merge with running state
    const float cm = smh[h2], cs = ssh[h2];
    const float mn = fmaxf(macc, cm);
    const float so = __expf(macc - mn);
    const float sn = __expf(cm - mn);
    lacc = lacc * so + cs * sn;
    acc0 *= so; acc1 *= so;
    macc = mn;
    // pass 2: weighted gather (no serial rescale chain)
#pragma unroll 2
    for (int el = 0; el < cnt; ++el) {
      int e = base + el;
      int s = csr_src[e];
      int r = csr_et[e];
      float p = slog[el * 8 + h2] * sn;
      float2 tv = load2bf(&t[((size_t)r * MPAD + s) * HD + 2 * tid]);
      acc0 = fmaf(p, tv.x, acc0);
      acc1 = fmaf(p, tv.y, acc1);
    }
    __syncthreads();  // slog reused next chunk
  }

  const float inv = 1.f / (lacc + 1e-16f);
  const float v0 = acc0 * inv, v1 = acc1 * inv;
  if (CONCAT) {
    float2 bb = *(const float2*)&bias[2 * tid];
    *(float2*)&out[(size_t)n * HD + 2 * tid] = make_float2(v0 + bb.x, v1 + bb.y);
  } else {
    float* sm = slog;  // reuse (post-sync)
    sm[2 * tid] = v0; sm[2 * tid + 1] = v1;
    __syncthreads();
    if (tid < DOUT) {
      float s = 0.f;
#pragma unroll
      for (int hh = 0; hh < NHEAD; ++hh) s += sm[hh * DOUT + tid];
      out[(size_t)n * DOUT + tid] = s * 0.125f + bias[tid];
    }
  }
}

// ---------- launch ----------
static void run_pipeline(const float* x, const int* ei, const int* et, const float* ea,
                         const float* W1, const float* q1, const float* k1,
                         const float* We1, const float* e1, const float* b1,
                         const float* W2, const float* q2, const float* k2,
                         const float* We2, const float* e2, const float* b2,
                         float* out, float* hbuf, float* qkbuf, float* WQK,
                         unsigned short* A2, unsigned short* BT,
                         float* cvec, int* meta, int* deg, int* rowptr,
                         int* fill, int* csr_src, int* csr_et, float* csr_ea,
                         unsigned short* t, hipStream_t stream) {
  (void)hipMemsetAsync(meta, 0, 4, stream);
  (void)hipMemsetAsync(deg, 0, (size_t)NN * 4, stream);
  k_max_et<<<EE / 256, 256, 0, stream>>>(et, meta);
  k_hist<<<(ETOT + 255) / 256, 256, 0, stream>>>(ei, deg);
  k_scan<<<1, 1024, 0, stream>>>(deg, rowptr, fill);
  k_scatter<<<(ETOT + 255) / 256, 256, 0, stream>>>(ei, et, ea, meta, fill,
                                                    csr_src, csr_et, csr_ea);
  // layer 1 (F=256, Kp=512)
  k_cvec<<<1, 64, 0, stream>>>(We1, e1, cvec);
  k_wqk<<<RREL * 256 * 16 / 256, 256, 0, stream>>>(W1, q1, k1, WQK, 256);
  k_asplit<<<(NN * 64 + 255) / 256, 256, 0, stream>>>(x, A2, 256);
  k_bsplit<<<dim3(4, 8, RREL), 256, 0, stream>>>(W1, BT, 256);
  k_mgemm<<<1008, 512, 0, stream>>>(A2, BT, t, 512);
  k_gemm<<<125, 256, 0, stream>>>(x, WQK, qkbuf, 256);
  k_attn<1><<<NN, 256, 0, stream>>>(t, qkbuf, cvec, rowptr, csr_src, csr_et,
                                    csr_ea, b1, hbuf);
  // layer 2 (F=512, Kp=1024)
  k_cvec<<<1, 64, 0, stream>>>(We2, e2, cvec);
  k_wqk<<<RREL * HD * 16 / 256, 256, 0, stream>>>(W2, q2, k2, WQK, HD);
  k_asplit<<<(NN * 128 + 255) / 256, 256, 0, stream>>>(hbuf, A2, HD);
  k_bsplit<<<dim3(8, 8, RREL), 256, 0, stream>>>(W2, BT, HD);
  k_mgemm<<<1008, 512, 0, stream>>>(A2, BT, t, 1024);
  k_gemm<<<125, 256, 0, stream>>>(hbuf, WQK, qkbuf, HD);
  k_attn<0><<<NN, 256, 0, stream>>>(t, qkbuf, cvec, rowptr, csr_src, csr_et,
                                    csr_ea, b2, out);
}

extern "C" void kernel_launch(void* const* d_in, const int* in_sizes, int n_in,
                              void* d_out, int out_size, void* d_ws, size_t ws_size,
                              hipStream_t stream) {
  const float* x   = (const float*)d_in[0];
  const int*   ei  = (const int*)d_in[1];
  const int*   et  = (const int*)d_in[2];
  const float* ea  = (const float*)d_in[3];
  const float* W1  = (const float*)d_in[4];
  const float* q1  = (const float*)d_in[5];
  const float* k1  = (const float*)d_in[6];
  const float* We1 = (const float*)d_in[7];
  const float* e1  = (const float*)d_in[8];
  const float* b1  = (const float*)d_in[9];
  const float* W2  = (const float*)d_in[10];
  const float* q2  = (const float*)d_in[11];
  const float* k2  = (const float*)d_in[12];
  const float* We2 = (const float*)d_in[13];
  const float* e2  = (const float*)d_in[14];
  const float* b2  = (const float*)d_in[15];
  float* out = (float*)d_out;

  char* w = (char*)d_ws;
  auto alloc = [&](size_t bytes) {
    char* p = w;
    w += (bytes + 255) & ~(size_t)255;
    return p;
  };
  float* hbuf   = (float*)alloc((size_t)NN * HD * 4);
  float* qkbuf  = (float*)alloc((size_t)NN * 128 * 4);
  float* WQK    = (float*)alloc((size_t)HD * 128 * 4);
  unsigned short* A2 = (unsigned short*)alloc((size_t)MPAD * 2 * HD * 2);
  unsigned short* BT = (unsigned short*)alloc((size_t)RREL * HD * 2 * HD * 2);
  float* cvec   = (float*)alloc(64);
  int*   meta   = (int*)alloc(64);
  int*   deg    = (int*)alloc((size_t)NN * 4);
  int*   rowptr = (int*)alloc((size_t)(NN + 1) * 4);
  int*   fill   = (int*)alloc((size_t)NN * 4);
  int*   csr_src= (int*)alloc((size_t)ETOT * 4);
  int*   csr_et = (int*)alloc((size_t)ETOT * 4);
  float* csr_ea = (float*)alloc((size_t)ETOT * 4);
  unsigned short* t = (unsigned short*)alloc((size_t)RREL * MPAD * HD * 2);
  (void)ws_size;

  run_pipeline(x, ei, et, ea, W1, q1, k1, We1, e1, b1,
               W2, q2, k2, We2, e2, b2, out, hbuf, qkbuf, WQK, A2, BT,
               cvec, meta, deg, rowptr, fill, csr_src, csr_et, csr_ea,
               t, stream);
}

// Round 9
// 691.159 us; speedup vs baseline: 1.2725x; 1.1204x over previous
//
#include <hip/hip_runtime.h>
#include <hip/hip_bf16.h>
#include <cstdint>
#include <cstddef>

#define NN 16000
#define MPAD 16128
#define EE 256000
#define ETOT (EE + NN)
#define RREL 8
#define NHEAD 8
#define DOUT 64
#define HD 512
#define NEG 0.2f

typedef unsigned int u32;
typedef short bf16x8 __attribute__((ext_vector_type(8)));
typedef float f32x4 __attribute__((ext_vector_type(4)));

// ---------- helpers ----------
__device__ inline unsigned short f2bf(float f) {
  u32 i = __float_as_uint(f);
  u32 r = (i + 0x7fff + ((i >> 16) & 1)) >> 16;  // RNE, finite values
  return (unsigned short)r;
}
__device__ inline float bf2f(unsigned short h) {
  return __uint_as_float((u32)h << 16);
}
__device__ inline void g2lds16(const void* g, void* lds) {
  __builtin_amdgcn_global_load_lds(
      (const __attribute__((address_space(1))) unsigned int*)g,
      (__attribute__((address_space(3))) unsigned int*)lds, 16, 0, 0);
}

// ---------- preprocessing ----------
__global__ void k_max_et(const int* __restrict__ et, int* meta) {
  int e = blockIdx.x * 256 + threadIdx.x;
  if (e < EE) atomicMax(&meta[0], et[e]);
}

__global__ void k_hist(const int* __restrict__ ei, int* __restrict__ deg) {
  int e = blockIdx.x * 256 + threadIdx.x;
  if (e >= ETOT) return;
  int dst = (e < EE) ? ei[EE + e] : (e - EE);
  atomicAdd(&deg[dst], 1);
}

__global__ __launch_bounds__(1024) void k_scan(const int* __restrict__ deg,
                                               int* __restrict__ rowptr,
                                               int* __restrict__ fill) {
  __shared__ int sm[1024];
  __shared__ int carry;
  if (threadIdx.x == 0) carry = 0;
  __syncthreads();
  for (int base = 0; base < NN; base += 1024) {
    int i = base + threadIdx.x;
    int v = (i < NN) ? deg[i] : 0;
    sm[threadIdx.x] = v;
    __syncthreads();
    for (int off = 1; off < 1024; off <<= 1) {
      int t = (threadIdx.x >= off) ? sm[threadIdx.x - off] : 0;
      __syncthreads();
      sm[threadIdx.x] += t;
      __syncthreads();
    }
    int incl = sm[threadIdx.x] + carry;
    if (i < NN) { rowptr[i] = incl - v; fill[i] = incl - v; }
    __syncthreads();
    if (threadIdx.x == 1023) carry = incl;
    __syncthreads();
  }
  if (threadIdx.x == 0) rowptr[NN] = carry;
}

__global__ void k_scatter(const int* __restrict__ ei, const int* __restrict__ et,
                          const float* __restrict__ ea, const int* __restrict__ meta,
                          int* __restrict__ fill, int* __restrict__ csr_src,
                          int* __restrict__ csr_et, float* __restrict__ csr_ea) {
  int e = blockIdx.x * 256 + threadIdx.x;
  if (e >= ETOT) return;
  int src, dst, r; float a;
  if (e < EE) { src = ei[e]; dst = ei[EE + e]; r = et[e]; a = ea[e]; }
  else { src = dst = e - EE; r = (meta[0] + 1) & (RREL - 1); a = 0.5f; }
  int pos = atomicAdd(&fill[dst], 1);
  csr_src[pos] = src; csr_et[pos] = r; csr_ea[pos] = a;
}

// ---------- per-layer small precomputes ----------
__global__ void k_cvec(const float* __restrict__ We, const float* __restrict__ e,
                       float* __restrict__ cvec) {
  int j = threadIdx.x;
  if (j >= NHEAD) return;
  float acc = 0.f;
  for (int h = 0; h < HD; ++h) acc += We[h] * e[h * NHEAD + j];
  cvec[j] = acc;
}

// WQK[f, r*16 + j] : j<8 -> W[r,f,:]@q[:,j] ; j>=8 -> W[r,f,:]@k[:,j-8]
__global__ void k_wqk(const float* __restrict__ W, const float* __restrict__ q,
                      const float* __restrict__ k, float* __restrict__ WQK, int F) {
  int g = blockIdx.x * 256 + threadIdx.x;
  int j = g & 15;
  int rf = g >> 4;  // r*F + f
  int r = rf / F, f = rf % F;
  const float* wrow = W + (size_t)rf * HD;
  const float* qk = ((j < 8) ? q : k) + (j & 7);
  float acc = 0.f;
  for (int h = 0; h < HD; ++h) acc += wrow[h] * qk[(size_t)h * NHEAD];
  WQK[(size_t)f * 128 + r * 16 + j] = acc;
}

// ---------- split-bf16 operand builders (2-term: A=[hi|lo], B=[hi;hi]) ----
__global__ void k_asplit(const float* __restrict__ in, unsigned short* __restrict__ A2,
                         int F) {
  long idx = (long)blockIdx.x * 256 + threadIdx.x;  // over NN * F/4
  long total = (long)NN * (F >> 2);
  if (idx >= total) return;
  int row = (int)(idx / (F >> 2));
  int c4 = (int)(idx % (F >> 2)) << 2;
  float4 v = *(const float4*)&in[(size_t)row * F + c4];
  ushort4 hi, lo;
  hi.x = f2bf(v.x); hi.y = f2bf(v.y); hi.z = f2bf(v.z); hi.w = f2bf(v.w);
  lo.x = f2bf(v.x - bf2f(hi.x)); lo.y = f2bf(v.y - bf2f(hi.y));
  lo.z = f2bf(v.z - bf2f(hi.z)); lo.w = f2bf(v.w - bf2f(hi.w));
  unsigned short* base = A2 + (size_t)row * 2 * F;
  *(ushort4*)&base[c4] = hi;
  *(ushort4*)&base[F + c4] = lo;
}

// W: [R][F][512] f32 -> BT: flattened [4096 cols][2F] bf16 (col-major B)
__global__ __launch_bounds__(256) void k_bsplit(const float* __restrict__ W,
                                                unsigned short* __restrict__ BT, int F) {
  int f0 = blockIdx.x * 64, c0 = blockIdx.y * 64, r = blockIdx.z;
  __shared__ float tile[64][65];
  int tid = threadIdx.x;
  int i0 = tid >> 6;   // 0..3
  int j = tid & 63;
  const float* Wr = W + (size_t)r * F * 512;
  for (int i = i0; i < 64; i += 4)
    tile[i][j] = Wr[(size_t)(f0 + i) * 512 + c0 + j];
  __syncthreads();
  unsigned short* Br = BT + (size_t)r * 512 * 2 * F;
  for (int c = i0; c < 64; c += 4) {
    float v = tile[j][c];  // W[r][f0+j][c0+c]
    unsigned short hi = f2bf(v);
    unsigned short* dst = Br + (size_t)(c0 + c) * 2 * F + f0 + j;
    dst[0] = hi; dst[F] = hi;
  }
}

// ---------- MFMA GEMM: C = A2[16128 x Kp] @ BT^T (N=4096 flat) ----------
// BM=BN=256, BK=32, 8 waves (2M x 4N, 128x64 each), 3 LDS buffers (96 KB),
// prefetch distance 2 with counted vmcnt(4) -- loads stay in flight across
// barriers, no drain in the main loop (T3+T4). Fragment-ordered LDS ->
// conflict-free ds_read_b128. Per-wave private epilogue transpose.
__global__ __launch_bounds__(512, 2) void k_mgemm(const unsigned short* __restrict__ A2,
                                                  const unsigned short* __restrict__ BT,
                                                  unsigned short* __restrict__ Ct,
                                                  int Kp) {
  const int bid = blockIdx.x;
  const int v = (bid & 7) * 126 + (bid >> 3);   // 1008 = 8*126, bijective
  const int mb = v >> 4;                        // 0..62 (m slow)
  const int nb = v & 15;                        // n fastest: A-panel L2-reuse
  const int m0 = mb << 8;
  const int n0 = nb << 8;

  __shared__ __align__(16) unsigned short smem[49152];  // 96 KB
  // A: buf b at [b*8192], 16 frags x 512 shorts; B: at [24576 + b*8192]

  const int tid = threadIdx.x;
  const int wid = tid >> 6;
  const int lane = tid & 63;
  const int wr = wid >> 2;     // 0..1 (m half)
  const int wc = wid & 3;      // 0..3 (n quarter)
  const int rlow = lane & 15;
  const int kch = lane >> 4;   // 0..3

  const unsigned short* srcA[2];
  const unsigned short* srcB[2];
  int dstOff[2];
#pragma unroll
  for (int p = 0; p < 2; ++p) {
    int fr = (p << 3) + wid;   // 0..15
    srcA[p] = A2 + (size_t)(m0 + fr * 16 + rlow) * Kp + kch * 8;
    srcB[p] = BT + (size_t)(n0 + fr * 16 + rlow) * Kp + kch * 8;
    dstOff[p] = fr * 512;
  }

  f32x4 acc[8][4] = {};
  const int nt = Kp >> 5;

  // prologue: stage tiles 0,1 into buffers 0,1 (8 vm-ops per thread)
#pragma unroll
  for (int tp = 0; tp < 2; ++tp) {
    const int ko = tp << 5;
#pragma unroll
    for (int p = 0; p < 2; ++p) {
      g2lds16(srcA[p] + ko, &smem[tp * 8192 + dstOff[p]]);
      g2lds16(srcB[p] + ko, &smem[24576 + tp * 8192 + dstOff[p]]);
    }
  }

  int buf = 0;
  for (int u = 0; u < nt; ++u) {
    if (u + 1 < nt)
      asm volatile("s_waitcnt vmcnt(4)" ::: "memory");
    else
      asm volatile("s_waitcnt vmcnt(0)" ::: "memory");
    __builtin_amdgcn_s_barrier();
    asm volatile("" ::: "memory");
    if (u + 2 < nt) {
      int nb2 = buf + 2; if (nb2 >= 3) nb2 -= 3;
      const int ko = (u + 2) << 5;
#pragma unroll
      for (int p = 0; p < 2; ++p) {
        g2lds16(srcA[p] + ko, &smem[nb2 * 8192 + dstOff[p]]);
        g2lds16(srcB[p] + ko, &smem[24576 + nb2 * 8192 + dstOff[p]]);
      }
    }
    const unsigned short* Ab = smem + buf * 8192;
    const unsigned short* Bb = smem + 24576 + buf * 8192;
    bf16x8 af[8], bfv[4];
#pragma unroll
    for (int i = 0; i < 8; ++i)
      af[i] = *(const bf16x8*)&Ab[(wr * 8 + i) * 512 + lane * 8];
#pragma unroll
    for (int j = 0; j < 4; ++j)
      bfv[j] = *(const bf16x8*)&Bb[(wc * 4 + j) * 512 + lane * 8];
    __builtin_amdgcn_s_setprio(1);
#pragma unroll
    for (int i = 0; i < 8; ++i)
#pragma unroll
      for (int j = 0; j < 4; ++j)
        acc[i][j] = __builtin_amdgcn_mfma_f32_16x16x32_bf16(af[i], bfv[j],
                                                            acc[i][j], 0, 0, 0);
    __builtin_amdgcn_s_setprio(0);
    buf = (buf == 2) ? 0 : buf + 1;
  }

  // ---- epilogue: per-wave private LDS transpose (no cross-wave sync) ----
  __syncthreads();
  float* epsW = (float*)smem + wid * 1344;  // 64 cols x 21 pad
  const int rowL = lane & 15;
  const int cseg = lane >> 4;
  const int colfull0 = n0 + wc * 64;
  const int rr = colfull0 >> 9;
  const int hbase = (colfull0 & 511) + cseg * 16;
#pragma unroll
  for (int i = 0; i < 8; ++i) {
#pragma unroll
    for (int j = 0; j < 4; ++j)
      *(f32x4*)&epsW[(j * 16 + rlow) * 21 + kch * 4] = acc[i][j];
    float vals[16];
#pragma unroll
    for (int c = 0; c < 16; ++c) vals[c] = epsW[(cseg * 16 + c) * 21 + rowL];
    const int rowg = m0 + wr * 128 + i * 16 + rowL;
    unsigned short* dst = Ct + ((size_t)rr * MPAD + rowg) * HD + hbase;
    uint4 w0, w1;
    w0.x = (u32)f2bf(vals[0])  | ((u32)f2bf(vals[1])  << 16);
    w0.y = (u32)f2bf(vals[2])  | ((u32)f2bf(vals[3])  << 16);
    w0.z = (u32)f2bf(vals[4])  | ((u32)f2bf(vals[5])  << 16);
    w0.w = (u32)f2bf(vals[6])  | ((u32)f2bf(vals[7])  << 16);
    w1.x = (u32)f2bf(vals[8])  | ((u32)f2bf(vals[9])  << 16);
    w1.y = (u32)f2bf(vals[10]) | ((u32)f2bf(vals[11]) << 16);
    w1.z = (u32)f2bf(vals[12]) | ((u32)f2bf(vals[13]) << 16);
    w1.w = (u32)f2bf(vals[14]) | ((u32)f2bf(vals[15]) << 16);
    *(uint4*)dst = w0;
    *(uint4*)(dst + 8) = w1;
  }
}

// ---------- small fp32 GEMM (layer-1 qkbuf): C = A @ B, B:[F][128] -------
__global__ __launch_bounds__(256) void k_gemm(const float* __restrict__ A,
                                              const float* __restrict__ B,
                                              float* __restrict__ C, int F) {
  const int m0 = blockIdx.x * 128;
  __shared__ float As[16][132];
  __shared__ float Bs[16][132];
  const int tid = threadIdx.x;
  const int arow = tid >> 2;
  const int acol = (tid & 3) << 2;
  const int brow = tid >> 5;
  const int bcol = (tid & 31) << 2;
  const int tr = ((tid >> 4) & 15) << 2;
  const int tc = (tid & 15) << 2;
  float acc[8][8] = {};
  for (int k0 = 0; k0 < F; k0 += 16) {
    float4 a0 = *(const float4*)&A[(size_t)(m0 + arow) * F + k0 + acol];
    float4 a1 = *(const float4*)&A[(size_t)(m0 + arow + 64) * F + k0 + acol];
    float4 b0 = *(const float4*)&B[(size_t)(k0 + brow) * 128 + bcol];
    float4 b1 = *(const float4*)&B[(size_t)(k0 + brow + 8) * 128 + bcol];
    As[acol + 0][arow] = a0.x; As[acol + 1][arow] = a0.y;
    As[acol + 2][arow] = a0.z; As[acol + 3][arow] = a0.w;
    As[acol + 0][arow + 64] = a1.x; As[acol + 1][arow + 64] = a1.y;
    As[acol + 2][arow + 64] = a1.z; As[acol + 3][arow + 64] = a1.w;
    *(float4*)&Bs[brow][bcol] = b0;
    *(float4*)&Bs[brow + 8][bcol] = b1;
    __syncthreads();
#pragma unroll
    for (int k = 0; k < 16; ++k) {
      float a[8], b[8];
      *(float4*)(a) = *(const float4*)&As[k][tr];
      *(float4*)(a + 4) = *(const float4*)&As[k][tr + 64];
      *(float4*)(b) = *(const float4*)&Bs[k][tc];
      *(float4*)(b + 4) = *(const float4*)&Bs[k][tc + 64];
#pragma unroll
      for (int i = 0; i < 8; ++i)
#pragma unroll
        for (int j = 0; j < 8; ++j)
          acc[i][j] = fmaf(a[i], b[j], acc[i][j]);
    }
    __syncthreads();
  }
#pragma unroll
  for (int i = 0; i < 8; ++i) {
    int row = m0 + tr + ((i < 4) ? i : (60 + i));
    *(float4*)&C[(size_t)row * 128 + tc] = make_float4(acc[i][0], acc[i][1], acc[i][2], acc[i][3]);
    *(float4*)&C[(size_t)row * 128 + tc + 64] = make_float4(acc[i][4], acc[i][5], acc[i][6], acc[i][7]);
  }
}

// ---------- layer-2 qkbuf GEMM: A from hi|lo bf16 pairs (stride 1024) -----
__global__ __launch_bounds__(256) void k_gemm2(const unsigned short* __restrict__ A2,
                                               const float* __restrict__ B,
                                               float* __restrict__ C) {
  const int m0 = blockIdx.x * 128;
  __shared__ float As[16][132];
  __shared__ float Bs[16][132];
  const int tid = threadIdx.x;
  const int arow = tid >> 2;
  const int acol = (tid & 3) << 2;
  const int brow = tid >> 5;
  const int bcol = (tid & 31) << 2;
  const int tr = ((tid >> 4) & 15) << 2;
  const int tc = (tid & 15) << 2;
  float acc[8][8] = {};
  for (int k0 = 0; k0 < 512; k0 += 16) {
    ushort4 h0 = *(const ushort4*)&A2[(size_t)(m0 + arow) * 1024 + k0 + acol];
    ushort4 l0 = *(const ushort4*)&A2[(size_t)(m0 + arow) * 1024 + 512 + k0 + acol];
    ushort4 h1 = *(const ushort4*)&A2[(size_t)(m0 + arow + 64) * 1024 + k0 + acol];
    ushort4 l1 = *(const ushort4*)&A2[(size_t)(m0 + arow + 64) * 1024 + 512 + k0 + acol];
    float4 a0 = make_float4(bf2f(h0.x) + bf2f(l0.x), bf2f(h0.y) + bf2f(l0.y),
                            bf2f(h0.z) + bf2f(l0.z), bf2f(h0.w) + bf2f(l0.w));
    float4 a1 = make_float4(bf2f(h1.x) + bf2f(l1.x), bf2f(h1.y) + bf2f(l1.y),
                            bf2f(h1.z) + bf2f(l1.z), bf2f(h1.w) + bf2f(l1.w));
    float4 b0 = *(const float4*)&B[(size_t)(k0 + brow) * 128 + bcol];
    float4 b1 = *(const float4*)&B[(size_t)(k0 + brow + 8) * 128 + bcol];
    As[acol + 0][arow] = a0.x; As[acol + 1][arow] = a0.y;
    As[acol + 2][arow] = a0.z; As[acol + 3][arow] = a0.w;
    As[acol + 0][arow + 64] = a1.x; As[acol + 1][arow + 64] = a1.y;
    As[acol + 2][arow + 64] = a1.z; As[acol + 3][arow + 64] = a1.w;
    *(float4*)&Bs[brow][bcol] = b0;
    *(float4*)&Bs[brow + 8][bcol] = b1;
    __syncthreads();
#pragma unroll
    for (int k = 0; k < 16; ++k) {
      float a[8], b[8];
      *(float4*)(a) = *(const float4*)&As[k][tr];
      *(float4*)(a + 4) = *(const float4*)&As[k][tr + 64];
      *(float4*)(b) = *(const float4*)&Bs[k][tc];
      *(float4*)(b + 4) = *(const float4*)&Bs[k][tc + 64];
#pragma unroll
      for (int i = 0; i < 8; ++i)
#pragma unroll
        for (int j = 0; j < 8; ++j)
          acc[i][j] = fmaf(a[i], b[j], acc[i][j]);
    }
    __syncthreads();
  }
#pragma unroll
  for (int i = 0; i < 8; ++i) {
    int row = m0 + tr + ((i < 4) ? i : (60 + i));
    *(float4*)&C[(size_t)row * 128 + tc] = make_float4(acc[i][0], acc[i][1], acc[i][2], acc[i][3]);
    *(float4*)&C[(size_t)row * 128 + tc + 64] = make_float4(acc[i][4], acc[i][5], acc[i][6], acc[i][7]);
  }
}

// ---------- fused attention: one WAVE per dst node, 4 nodes/block --------
// lane owns 8 columns (16B dwordx4 loads); head state replicated across the
// 8 lanes of each head-group (no shuffles). Online softmax w/ rescale-skip.
// CONCAT=1: emits hi|lo bf16 split directly into A2 (next layer's operand).
template <int CONCAT>
__global__ __launch_bounds__(256) void k_attn(const unsigned short* __restrict__ t,
    const float* __restrict__ qkbuf, const float* __restrict__ cvec,
    const int* __restrict__ rowptr, const int* __restrict__ csr_src,
    const int* __restrict__ csr_et, const float* __restrict__ csr_ea,
    const float* __restrict__ bias, float* __restrict__ out,
    unsigned short* __restrict__ A2out) {
  const int wv = threadIdx.x >> 6;
  const int lane = threadIdx.x & 63;
  const int n = blockIdx.x * 4 + wv;
  const int h = lane >> 3;
  const int c0 = lane << 3;  // 8 cols per lane
  const int e0 = rowptr[n], e1 = rowptr[n + 1];
  const float ch = cvec[h];
  const float* qrow = qkbuf + (size_t)n * 128;
  float m = -1e30f, l = 0.f;
  float acc[8] = {};
  for (int e = e0; e < e1; ++e) {
    const int s = csr_src[e];
    const int r = csr_et[e];
    const float a = csr_ea[e];
    float logit = qrow[r * 16 + h] + qkbuf[(size_t)s * 128 + r * 16 + 8 + h] + a * ch;
    logit = (logit > 0.f) ? logit : NEG * logit;
    const uint4 tv = *(const uint4*)&t[((size_t)r * MPAD + s) * HD + c0];
    float p;
    if (logit <= m) {
      p = __expf(logit - m);
    } else {
      const float sc = __expf(m - logit);
      l *= sc;
#pragma unroll
      for (int c = 0; c < 8; ++c) acc[c] *= sc;
      m = logit;
      p = 1.f;
    }
    l += p;
    acc[0] = fmaf(p, __uint_as_float((tv.x & 0xffffu) << 16), acc[0]);
    acc[1] = fmaf(p, __uint_as_float(tv.x & 0xffff0000u), acc[1]);
    acc[2] = fmaf(p, __uint_as_float((tv.y & 0xffffu) << 16), acc[2]);
    acc[3] = fmaf(p, __uint_as_float(tv.y & 0xffff0000u), acc[3]);
    acc[4] = fmaf(p, __uint_as_float((tv.z & 0xffffu) << 16), acc[4]);
    acc[5] = fmaf(p, __uint_as_float(tv.z & 0xffff0000u), acc[5]);
    acc[6] = fmaf(p, __uint_as_float((tv.w & 0xffffu) << 16), acc[6]);
    acc[7] = fmaf(p, __uint_as_float(tv.w & 0xffff0000u), acc[7]);
  }
  const float inv = 1.f / (l + 1e-16f);
  if (CONCAT) {
    unsigned short his[8], los[8];
#pragma unroll
    for (int c = 0; c < 8; ++c) {
      const float vv = fmaf(acc[c], inv, bias[c0 + c]);
      const unsigned short hi = f2bf(vv);
      his[c] = hi;
      los[c] = f2bf(vv - bf2f(hi));
    }
    uint4 wh, wl;
    wh.x = (u32)his[0] | ((u32)his[1] << 16);
    wh.y = (u32)his[2] | ((u32)his[3] << 16);
    wh.z = (u32)his[4] | ((u32)his[5] << 16);
    wh.w = (u32)his[6] | ((u32)his[7] << 16);
    wl.x = (u32)los[0] | ((u32)los[1] << 16);
    wl.y = (u32)los[2] | ((u32)los[3] << 16);
    wl.z = (u32)los[4] | ((u32)los[5] << 16);
    wl.w = (u32)los[6] | ((u32)los[7] << 16);
    *(uint4*)&A2out[(size_t)n * 1024 + c0] = wh;
    *(uint4*)&A2out[(size_t)n * 1024 + 512 + c0] = wl;
  } else {
    __shared__ float sm[4][HD];
#pragma unroll
    for (int c = 0; c < 8; ++c) sm[wv][c0 + c] = acc[c] * inv;
    __syncthreads();
    const int d = lane;
    float s = 0.f;
#pragma unroll
    for (int hh = 0; hh < NHEAD; ++hh) s += sm[wv][hh * 64 + d];
    out[(size_t)n * DOUT + d] = s * 0.125f + bias[d];
  }
}

// ---------- launch ----------
static void run_pipeline(const float* x, const int* ei, const int* et, const float* ea,
                         const float* W1, const float* q1, const float* k1,
                         const float* We1, const float* e1, const float* b1,
                         const float* W2, const float* q2, const float* k2,
                         const float* We2, const float* e2, const float* b2,
                         float* out, float* qkbuf, float* WQK,
                         unsigned short* A2, unsigned short* BT,
                         float* cvec, int* meta, int* deg, int* rowptr,
                         int* fill, int* csr_src, int* csr_et, float* csr_ea,
                         unsigned short* t, hipStream_t stream) {
  (void)hipMemsetAsync(meta, 0, 4, stream);
  (void)hipMemsetAsync(deg, 0, (size_t)NN * 4, stream);
  k_max_et<<<EE / 256, 256, 0, stream>>>(et, meta);
  k_hist<<<(ETOT + 255) / 256, 256, 0, stream>>>(ei, deg);
  k_scan<<<1, 1024, 0, stream>>>(deg, rowptr, fill);
  k_scatter<<<(ETOT + 255) / 256, 256, 0, stream>>>(ei, et, ea, meta, fill,
                                                    csr_src, csr_et, csr_ea);
  // layer 1 (F=256, Kp=512): A2 row stride 512
  k_cvec<<<1, 64, 0, stream>>>(We1, e1, cvec);
  k_wqk<<<RREL * 256 * 16 / 256, 256, 0, stream>>>(W1, q1, k1, WQK, 256);
  k_asplit<<<(NN * 64 + 255) / 256, 256, 0, stream>>>(x, A2, 256);
  k_bsplit<<<dim3(4, 8, RREL), 256, 0, stream>>>(W1, BT, 256);
  k_mgemm<<<1008, 512, 0, stream>>>(A2, BT, t, 512);
  k_gemm<<<125, 256, 0, stream>>>(x, WQK, qkbuf, 256);
  k_attn<1><<<NN / 4, 256, 0, stream>>>(t, qkbuf, cvec, rowptr, csr_src, csr_et,
                                        csr_ea, b1, nullptr, A2);  // A2 stride 1024
  // layer 2 (F=512, Kp=1024): A2 written by attn<1>
  k_cvec<<<1, 64, 0, stream>>>(We2, e2, cvec);
  k_wqk<<<RREL * HD * 16 / 256, 256, 0, stream>>>(W2, q2, k2, WQK, HD);
  k_bsplit<<<dim3(8, 8, RREL), 256, 0, stream>>>(W2, BT, HD);
  k_mgemm<<<1008, 512, 0, stream>>>(A2, BT, t, 1024);
  k_gemm2<<<125, 256, 0, stream>>>(A2, WQK, qkbuf);
  k_attn<0><<<NN / 4, 256, 0, stream>>>(t, qkbuf, cvec, rowptr, csr_src, csr_et,
                                        csr_ea, b2, out, nullptr);
}

extern "C" void kernel_launch(void* const* d_in, const int* in_sizes, int n_in,
                              void* d_out, int out_size, void* d_ws, size_t ws_size,
                              hipStream_t stream) {
  const float* x   = (const float*)d_in[0];
  const int*   ei  = (const int*)d_in[1];
  const int*   et  = (const int*)d_in[2];
  const float* ea  = (const float*)d_in[3];
  const float* W1  = (const float*)d_in[4];
  const float* q1  = (const float*)d_in[5];
  const float* k1  = (const float*)d_in[6];
  const float* We1 = (const float*)d_in[7];
  const float* e1  = (const float*)d_in[8];
  const float* b1  = (const float*)d_in[9];
  const float* W2  = (const float*)d_in[10];
  const float* q2  = (const float*)d_in[11];
  const float* k2  = (const float*)d_in[12];
  const float* We2 = (const float*)d_in[13];
  const float* e2  = (const float*)d_in[14];
  const float* b2  = (const float*)d_in[15];
  float* out = (float*)d_out;

  char* w = (char*)d_ws;
  auto alloc = [&](size_t bytes) {
    char* p = w;
    w += (bytes + 255) & ~(size_t)255;
    return p;
  };
  float* qkbuf  = (float*)alloc((size_t)NN * 128 * 4);
  float* WQK    = (float*)alloc((size_t)HD * 128 * 4);
  unsigned short* A2 = (unsigned short*)alloc((size_t)MPAD * 2 * HD * 2);
  unsigned short* BT = (unsigned short*)alloc((size_t)RREL * HD * 2 * HD * 2);
  float* cvec   = (float*)alloc(64);
  int*   meta   = (int*)alloc(64);
  int*   deg    = (int*)alloc((size_t)NN * 4);
  int*   rowptr = (int*)alloc((size_t)(NN + 1) * 4);
  int*   fill   = (int*)alloc((size_t)NN * 4);
  int*   csr_src= (int*)alloc((size_t)ETOT * 4);
  int*   csr_et = (int*)alloc((size_t)ETOT * 4);
  float* csr_ea = (float*)alloc((size_t)ETOT * 4);
  unsigned short* t = (unsigned short*)alloc((size_t)RREL * MPAD * HD * 2);
  (void)ws_size;

  run_pipeline(x, ei, et, ea, W1, q1, k1, We1, e1, b1,
               W2, q2, k2, We2, e2, b2, out, qkbuf, WQK, A2, BT,
               cvec, meta, deg, rowptr, fill, csr_src, csr_et, csr_ea,
               t, stream);
}